// Round 4
// baseline (1349.364 us; speedup 1.0000x reference)
//
#include <hip/hip_runtime.h>
#include <math.h>

typedef unsigned short u16;
typedef unsigned int u32;
typedef unsigned long long u64;
typedef __attribute__((ext_vector_type(8))) __bf16 bf16x8;
typedef __attribute__((ext_vector_type(4))) float f32x4;
typedef __attribute__((ext_vector_type(4))) _Float16 f16x4;

// ---------------- problem constants ----------------
#define MR   6144      // 48*128 rows (t-major: row = t*128 + bc)
#define KP1  320       // padded K for E=H=300
#define NPG  1280      // padded gate rows (1200 real, interleaved 4j+g)
#define NG   1200
#define WSEG 409600    // u16 elements per weight segment [1280][320]
#define UPSEG 409600   // u16 per U perm segment [80 T][10 kt][64 lane][8]
// G perm (f16 halves): tt*163840 + nt*16384 + half*8192 + wm*4096 + wn*2048 + (i*4+j)*256 + ln*4 + r
#define GT_H 163840

// ---------------- workspace layout (byte offsets, 16B aligned) ----------------
// NOTE: tagged h-exchange buffer HX (655,360 B) lives at OFF_ABF: the ABF region
// is dead during both lstm_sync calls (gemm_bt has fully consumed it), and the
// tag garbage it leaves in ABF's padded k-columns multiplies against zeroed
// B-rows (k>=300) in the next gemm, so it is harmless (and never Inf/NaN).
#define OFF_ABF    0UL           // bf16 [6144][320]            3,932,160
#define OFF_WBF    3932160UL     // bf16 4 x [1280][320]        3,276,800 (W only; U goes straight to UP)
#define OFF_WCF    10485760UL    // f32  [300][1800] folded fc1 2,160,000
#define OFF_BIAS   12645760UL    // f32  4 x 1200 interleaved      19,200
#define OFF_GF     12664960UL    // f16  perm                  15,728,640
#define OFF_GR     28393600UL    // f16  perm                  15,728,640
#define OFF_HB     44122240UL    // bf16 2 dirs x [128][320]      163,840
#define OFF_ENC    44286080UL    // f32  [128][600]               307,200
#define OFF_VB     44593280UL    // f32  8 x [64][600]          1,228,800
#define OFF_CO     45822080UL    // f32  8 x [64][300]            614,400
#define OFF_ATT    46436480UL    // f32  3 x 48*64                 36,864
#define OFF_PT     46473344UL    // f32  [2400][64] pooled^T      614,400
#define OFF_LG     47087744UL    // f32  64*300                    76,800
#define OFF_UP     47164544UL    // bf16 4 x Uperm              3,276,800

#define HX_BYTES   655360UL      // u64 [2 buf][2 dir][128 bcg][160 pair]

__device__ __forceinline__ float fsig(float x) { return 1.0f / (1.0f + __expf(-x)); }
__device__ __forceinline__ float ftanh(float x) { return 1.0f - 2.0f / (__expf(2.0f * x) + 1.0f); }

__device__ __forceinline__ u16 f2bf(float x) {
    union { float f; u32 u; } v; v.f = x;
    u32 r = v.u + 0x7fffu + ((v.u >> 16) & 1u);   // RNE
    return (u16)(r >> 16);
}
__device__ __forceinline__ float bf2f(u16 x) {
    union { u32 u; float f; } v; v.u = ((u32)x) << 16; return v.f;
}

__device__ __forceinline__ void gld_lds16(const u16* g, u16* l) {
    __builtin_amdgcn_global_load_lds(
        (const __attribute__((address_space(1))) unsigned int*)g,
        (__attribute__((address_space(3))) unsigned int*)l, 16, 0, 0);
}

// ---------------- fused preprocessing: gather + wconv(4W) + uperm(4U direct) + bconv + wcat ----
// block-range partition; all five sections are mutually independent (uperm reads fp32 U inputs
// directly instead of the bf16 WBF intermediate, removing the old wconv->uperm dependency).
#define PREP_B0 7680      // gather: MR*KP1/256
#define PREP_B1 14080     // + 4*NPG*KP1/256 = 6400
#define PREP_B2 20480     // + 4*UPSEG/256   = 6400
#define PREP_B3 20499     // + ceil(4*NG/256)= 19
#define PREP_B4 22609     // + ceil(540000/256) = 2110
__global__ __launch_bounds__(256) void prep_k(
    const int* __restrict__ x1, const int* __restrict__ x2, const float* __restrict__ emb,
    const float* __restrict__ w0, const float* __restrict__ w1,
    const float* __restrict__ w2, const float* __restrict__ w3,
    const float* __restrict__ u0, const float* __restrict__ u1,
    const float* __restrict__ u2, const float* __restrict__ u3,
    const float* __restrict__ b0i, const float* __restrict__ b0h,
    const float* __restrict__ b1i, const float* __restrict__ b1h,
    const float* __restrict__ b2i, const float* __restrict__ b2h,
    const float* __restrict__ b3i, const float* __restrict__ b3h,
    const float* __restrict__ f1w,
    u16* __restrict__ abf, u16* __restrict__ wbf, u16* __restrict__ up,
    float* __restrict__ bias, float* __restrict__ wc) {
    int bid = blockIdx.x;
    if (bid < PREP_B0) {
        int idx = bid * 256 + threadIdx.x;          // < MR*KP1 exactly
        int r = idx / KP1, k = idx % KP1;
        float v = 0.0f;
        if (k < 300) {
            int t = r >> 7, bc = r & 127;
            int tok = (bc < 64) ? x1[t * 64 + bc] : x2[t * 64 + bc - 64];
            v = emb[tok * 300 + k];
        }
        abf[idx] = f2bf(v);
    } else if (bid < PREP_B1) {
        int idx = (bid - PREP_B0) * 256 + threadIdx.x;   // < 4*NPG*KP1 exactly
        int s = idx / (NPG * KP1), rem = idx % (NPG * KP1);
        int r = rem / KP1, k = rem % KP1;
        const float* w = (s == 0) ? w0 : (s == 1) ? w1 : (s == 2) ? w2 : w3;
        float v = 0.0f;
        if (r < NG && k < 300) {
            int j = r >> 2, g = r & 3;
            v = w[(g * 300 + j) * 300 + k];
        }
        wbf[idx] = f2bf(v);
    } else if (bid < PREP_B2) {
        int idx = (bid - PREP_B1) * 256 + threadIdx.x;   // < 4*UPSEG exactly
        int seg = idx / UPSEG, pos = idx % UPSEG;
        int T = pos / 5120, kt = (pos / 512) % 10, l = (pos >> 3) & 63, e = pos & 7;
        int n = T * 16 + (l & 15);
        int k = kt * 32 + (l >> 4) * 8 + e;
        const float* us = (seg == 0) ? u0 : (seg == 1) ? u1 : (seg == 2) ? u2 : u3;
        float v = 0.0f;
        if (n < NG && k < 300) {
            int j = n >> 2, g = n & 3;
            v = us[(g * 300 + j) * 300 + k];
        }
        up[idx] = f2bf(v);
    } else if (bid < PREP_B3) {
        int idx = (bid - PREP_B2) * 256 + threadIdx.x;
        if (idx < 4 * NG) {
            int s = idx / NG, n = idx % NG;
            int j = n >> 2, g = n & 3;
            int src = g * 300 + j;
            const float* bi = (s == 0) ? b0i : (s == 1) ? b1i : (s == 2) ? b2i : b3i;
            const float* bh = (s == 0) ? b0h : (s == 1) ? b1h : (s == 2) ? b2h : b3h;
            bias[idx] = bi[src] + bh[src];
        }
    } else {
        int idx = (bid - PREP_B3) * 256 + threadIdx.x;
        if (idx < 300 * 1800) {
            int n = idx / 1800, k = idx % 1800;
            int nk = n * 2400 + k;
            float v;
            if (k < 600)       v = f1w[nk] + f1w[nk + 1800];
            else if (k < 1200) v = f1w[nk] - f1w[nk + 1200];
            else               v = f1w[nk];
            wc[idx] = v;
        }
    }
}

// ---------------- bf16 MFMA GEMM -> G in consumer-fragment-major f16 layout ----------------
// z = weight segment pair member: B = Wb + z*WSEG, bias = biasb + z*NG, out = z ? G1 : G0.
__global__ __launch_bounds__(256) void gemm_bt(const u16* __restrict__ A,
                                               const u16* __restrict__ Wb,
                                               const float* __restrict__ biasb,
                                               _Float16* __restrict__ G0,
                                               _Float16* __restrict__ G1) {
    __shared__ __align__(16) u16 smA[128 * 32];
    __shared__ __align__(16) u16 smB[128 * 32];
    int sidx = blockIdx.z;
    const u16* B = Wb + (size_t)sidx * WSEG;
    const float* bias = biasb + sidx * NG;
    _Float16* Gh = sidx ? G1 : G0;
    int m0 = blockIdx.x * 128, n0 = blockIdx.y * 128;
    int tid = threadIdx.x, ln = tid & 63;
    int wm = (tid >> 6) & 1, wn = tid >> 7;
    int lrow = ln & 15, lq = ln >> 4;
    f32x4 acc[4][4] = {};
    for (int k0 = 0; k0 < KP1; k0 += 32) {
#pragma unroll
        for (int p = 0; p < 2; p++) {
            int e = (p * 256 + tid) * 8;
            int r = e >> 5, kk = e & 31;
            gld_lds16(A + (size_t)(m0 + r) * KP1 + k0 + kk, smA + e);
            gld_lds16(B + (size_t)(n0 + r) * KP1 + k0 + kk, smB + e);
        }
        __syncthreads();
        bf16x8 av[4], bv[4];
#pragma unroll
        for (int i = 0; i < 4; i++) {
            av[i] = *(const bf16x8*)&smA[(wm * 64 + i * 16 + lrow) * 32 + lq * 8];
            bv[i] = *(const bf16x8*)&smB[(wn * 64 + i * 16 + lrow) * 32 + lq * 8];
        }
#pragma unroll
        for (int i = 0; i < 4; i++)
#pragma unroll
            for (int j = 0; j < 4; j++)
                acc[i][j] = __builtin_amdgcn_mfma_f32_16x16x32_bf16(av[i], bv[j], acc[i][j], 0, 0, 0);
        __syncthreads();
    }
    // perm store: half=wm (this wave's 64-row group), consumer wm = i>>1, i' = i&1
    size_t tb = (size_t)blockIdx.x * GT_H + (size_t)blockIdx.y * 16384
              + (size_t)wm * 8192 + (size_t)wn * 2048 + (size_t)ln * 4;
#pragma unroll
    for (int i = 0; i < 4; i++)
#pragma unroll
        for (int j = 0; j < 4; j++) {
            int n = n0 + wn * 64 + j * 16 + lrow;
            f16x4 v;
            if (n < NG) {
                float bb = bias[n];
#pragma unroll
                for (int r = 0; r < 4; r++) v[r] = (_Float16)(acc[i][j][r] + bb);
            } else {
                v = (f16x4)0;
            }
            *(f16x4*)(Gh + tb + (size_t)(i >> 1) * 4096 + (size_t)(((i & 1) * 4 + j)) * 256) = v;
        }
}

// ---------------- LSTM: gate-split, BARRIER-FREE tagged h exchange, partial-retry poll ----------
// grid (10 nt, 2 dir, 2 half), block 256 = 4 waves (wm = w&1 batch-quarter, wn = w>>1 gate-half).
// h exchange: u64 {tag=t+1 (hi32), 2xbf16 (lo32)} relaxed agent atomics (8B atomicity => tag-valid
// implies data-valid; no fences/drains/barriers). Poll: first pass reads all 40 contiguous u64/
// thread; retries are PREDICATED on a per-thread 40-bit miss mask (statically unrolled) so retry
// traffic only touches the not-yet-arrived producers' slices -- kills the L3 poll-contention loop.
// Two barriers per step (A: Hst ready; B: gates staged); the old post-store barrier was redundant.
// CRITICAL: h stores are UNCONDITIONAL (incl. padded j>=300 columns, h==0 there): the consumer
// polls all 160 pair-columns, so a guarded store deadlocks the poll (R3 bug).
__global__ __launch_bounds__(256, 1) void lstm_sync(const _Float16* __restrict__ Gf,
                                                    const _Float16* __restrict__ Gr,
                                                    const u16* __restrict__ Upf,
                                                    const u16* __restrict__ Upr,
                                                    u64* __restrict__ hx,
                                                    u16* __restrict__ hb) {
    int nt = blockIdx.x, dir = blockIdx.y, half = blockIdx.z;
    const _Float16* G = dir ? Gr : Gf;
    const u16* Up = dir ? Upr : Upf;

    int tid = threadIdx.x, ln = tid & 63, w = tid >> 6;
    int wm = w & 1, wn = w >> 1;
    int lrow = ln & 15, lq = ln >> 4;

    __shared__ __align__(16) u16 Ulds[80 * 512];    // 8 T x 10 kt x 64 x 8   (80 KB)
    __shared__ __align__(16) u32 Hst[64 * 160];     // tag-stripped h slab     (40 KB)
    __shared__ float P[64][132];                    // gate staging           (33.8 KB)

    // stage this block's U slice (linear copy, fragment-major)
    for (int p = 0; p < 20; p++) {
        int e = (p * 256 + tid) * 8;
        gld_lds16(Up + (size_t)nt * 40960 + e, Ulds + e);
    }
    __syncthreads();

    u32* HOw = (u32*)hb;

    int jp = tid & 15, bg = tid >> 4;
    float c[4][2];
#pragma unroll
    for (int q = 0; q < 4; q++) { c[q][0] = 0.0f; c[q][1] = 0.0f; }

    const _Float16* Gs = G + (size_t)nt * 16384 + (size_t)half * 8192
                       + (size_t)wm * 4096 + (size_t)wn * 2048 + (size_t)ln * 4;
    f16x4 gpre[8];
    {
        int ttg = dir ? 47 : 0;
        const _Float16* Gt = Gs + (size_t)ttg * GT_H;
#pragma unroll
        for (int f = 0; f < 8; f++) gpre[f] = *(const f16x4*)(Gt + (size_t)f * 256);
    }

    for (int t = 0; t < 48; t++) {
        // ---- cooperative tagged poll-load of this half's h slab (64 rows x 160 u64) ----
        {
            const u64* slab = hx + ((size_t)(t & 1) * 2 + dir) * 20480 + (size_t)half * 10240;
            u32 want = (u32)t;
            u32 hv[40];
            u64 miss = 0;
#pragma unroll
            for (int q = 0; q < 40; q++) {
                u64 x = __hip_atomic_load(slab + q * 256 + tid,
                                          __ATOMIC_RELAXED, __HIP_MEMORY_SCOPE_AGENT);
                hv[q] = (u32)x;
                miss |= ((u64)((u32)(x >> 32) != want)) << q;
            }
            while (miss) {
                __builtin_amdgcn_s_sleep(1);
#pragma unroll
                for (int q = 0; q < 40; q++) {
                    if (miss & (1ull << q)) {
                        u64 x = __hip_atomic_load(slab + q * 256 + tid,
                                                  __ATOMIC_RELAXED, __HIP_MEMORY_SCOPE_AGENT);
                        if ((u32)(x >> 32) == want) { hv[q] = (u32)x; miss &= ~(1ull << q); }
                    }
                }
            }
            // strip tags -> XOR-swizzled LDS (write side: consecutive cc per row -> conflict-free)
#pragma unroll
            for (int q = 0; q < 40; q++) {
                int idx = q * 256 + tid;
                int row = idx / 160, cc = idx - row * 160;
                Hst[row * 160 + (cc ^ ((row & 7) << 2))] = hv[q];
            }
        }
        __syncthreads();                             // A: Hst ready, prev-iter P reads done

        f32x4 acc[2][4];
#pragma unroll
        for (int i = 0; i < 2; i++)
#pragma unroll
            for (int j = 0; j < 4; j++) {
                f32x4 a;
#pragma unroll
                for (int r = 0; r < 4; r++) a[r] = (float)gpre[i * 4 + j][r];
                acc[i][j] = a;
            }

#pragma unroll
        for (int kt = 0; kt < 10; kt++) {
            bf16x8 av[2], bv[4];
#pragma unroll
            for (int i = 0; i < 2; i++) {
                int row = wm * 32 + i * 16 + lrow;
                int cc = (kt * 16 + lq * 4) ^ ((row & 7) << 2);
                av[i] = *(const bf16x8*)&Hst[row * 160 + cc];
            }
#pragma unroll
            for (int j = 0; j < 4; j++)
                bv[j] = *(const bf16x8*)&Ulds[((size_t)(wn * 4 + j) * 10 + kt) * 512 + ln * 8];
#pragma unroll
            for (int i = 0; i < 2; i++)
#pragma unroll
                for (int j = 0; j < 4; j++)
                    acc[i][j] = __builtin_amdgcn_mfma_f32_16x16x32_bf16(av[i], bv[j], acc[i][j], 0, 0, 0);
        }

        // stage gates to LDS
#pragma unroll
        for (int i = 0; i < 2; i++)
#pragma unroll
            for (int j = 0; j < 4; j++) {
                int col = wn * 64 + j * 16 + lrow;
#pragma unroll
                for (int r = 0; r < 4; r++)
                    P[wm * 32 + i * 16 + lq * 4 + r][col] = acc[i][j][r];
            }
        __syncthreads();                             // B: gates staged (also fences Hst reuse)

        // nonlinearity FIRST (h stores are the cross-block critical path), prefetch after.
        // UNCONDITIONAL store: padded j>=300 have exactly-zero gates -> h == 0 (uniform tags).
        {
            u64* hxo = hx + ((size_t)((t + 1) & 1) * 2 + dir) * 20480;
            u64 tagb = ((u64)(u32)(t + 1)) << 32;
#pragma unroll
            for (int q = 0; q < 4; q++) {
                int bc = bg * 4 + q;
                f32x4 g0 = *(const f32x4*)&P[bc][8 * jp];
                f32x4 g1 = *(const f32x4*)&P[bc][8 * jp + 4];
                float cn0 = fsig(g0[1]) * c[q][0] + fsig(g0[0]) * ftanh(g0[2]);
                float hn0 = fsig(g0[3]) * ftanh(cn0);
                float cn1 = fsig(g1[1]) * c[q][1] + fsig(g1[0]) * ftanh(g1[2]);
                float hn1 = fsig(g1[3]) * ftanh(cn1);
                c[q][0] = cn0; c[q][1] = cn1;
                u32 pk = (u32)f2bf(hn0) | ((u32)f2bf(hn1) << 16);
                int bcg = half * 64 + bc;
                size_t oi = (size_t)bcg * 160 + nt * 16 + jp;
                if (t < 47)
                    __hip_atomic_store(hxo + oi, (u64)pk | tagb,
                                       __ATOMIC_RELAXED, __HIP_MEMORY_SCOPE_AGENT);
                else
                    HOw[(size_t)dir * 20480 + oi] = pk;
            }
        }

        // prefetch next G (consumed next iteration; covered by the next poll phase)
        if (t < 47) {
            int ttg = dir ? 46 - t : t + 1;
            const _Float16* Gt = Gs + (size_t)ttg * GT_H;
#pragma unroll
            for (int f = 0; f < 8; f++) gpre[f] = *(const f16x4*)(Gt + (size_t)f * 256);
        }
        // no trailing barrier: barrier A (after next poll) orders P reads vs next P writes,
        // barrier B orders Hst reads vs next strip writes.
    }
}

// ---------------- final-h concat (batch-reversal quirk): [128][600] f32 ----------------
__global__ __launch_bounds__(256) void enc_k(const u16* __restrict__ hF,
                                             const u16* __restrict__ hR,
                                             float* __restrict__ enc) {
    int idx = blockIdx.x * 256 + threadIdx.x;
    if (idx >= 128 * 600) return;
    int bc = idx / 600, d = idx % 600;
    int seq = bc >> 6, b = bc & 63;
    enc[idx] = (d < 300) ? bf2f(hF[bc * KP1 + d])
                         : bf2f(hR[(seq * 64 + 63 - b) * KP1 + d - 300]);
}

// ---------------- build 8 coefficient vectors V[8][64][600] ----------------
__global__ __launch_bounds__(256) void vbuf_k(const float* __restrict__ enc,
                                              float* __restrict__ V) {
    int idx = blockIdx.x * 256 + threadIdx.x;
    if (idx >= 64 * 600) return;
    int b = idx / 600, d = idx % 600;
    float e1 = enc[b * 600 + d], e2 = enc[(64 + b) * 600 + d];
    float p = fmaxf(e2, 0.0f), nn = fminf(e2, 0.0f);
    V[0 * 38400 + idx] = e1;
    V[1 * 38400 + idx] = p;
    V[2 * 38400 + idx] = nn;
    V[3 * 38400 + idx] = e1 * p;
    V[4 * 38400 + idx] = e1 * nn;
    V[5 * 38400 + idx] = e2;
    V[6 * 38400 + idx] = e1;
    V[7 * 38400 + idx] = e1 * e2;
}

// ---------------- attention scalars (rank-1 collapse): AMX/AMN/SS [48][64] ----------------
__global__ __launch_bounds__(256) void attn_lite(const float* __restrict__ enc,
                                                 const float* __restrict__ x1m,
                                                 const float* __restrict__ x2m,
                                                 float* __restrict__ AMX,
                                                 float* __restrict__ AMN,
                                                 float* __restrict__ SS) {
    int b = blockIdx.x, tid = threadIdx.x;
    __shared__ float sc[48][49];
    __shared__ float rmx[4], rmn[4];
    __shared__ float MxMn[2];
    float mx = -3.4e38f, mn = 3.4e38f;
    for (int d = tid; d < 600; d += 256) {
        float p = enc[b * 600 + d] * enc[(64 + b) * 600 + d];
        mx = fmaxf(mx, p); mn = fminf(mn, p);
    }
    for (int off = 32; off; off >>= 1) {
        mx = fmaxf(mx, __shfl_down(mx, off));
        mn = fminf(mn, __shfl_down(mn, off));
    }
    if ((tid & 63) == 0) { rmx[tid >> 6] = mx; rmn[tid >> 6] = mn; }
    __syncthreads();
    if (tid == 0) {
        MxMn[0] = fmaxf(fmaxf(rmx[0], rmx[1]), fmaxf(rmx[2], rmx[3]));
        MxMn[1] = fminf(fminf(rmn[0], rmn[1]), fminf(rmn[2], rmn[3]));
    }
    __syncthreads();
    float Mx = MxMn[0], Mn = MxMn[1];
    for (int idx = tid; idx < 2304; idx += 256) {
        int i = idx / 48, j = idx % 48;
        float q = x1m[i * 64 + b] * x2m[j * 64 + b];
        sc[i][j] = (q > 0.0f) ? q * Mx : ((q < 0.0f) ? q * Mn : 0.0f);
    }
    __syncthreads();
    if (tid < 48) {
        int i = tid;
        float m = -3.4e38f;
        for (int j = 0; j < 48; j++) m = fmaxf(m, sc[i][j]);
        float sum = 0.0f;
        for (int j = 0; j < 48; j++) sum += expf(sc[i][j] - m) * x2m[j * 64 + b];
        float wmax = -3.4e38f, wmin = 3.4e38f;
        for (int j = 0; j < 48; j++) {
            float w = expf(sc[i][j] - m) * x2m[j * 64 + b] * x2m[j * 64 + b];
            wmax = fmaxf(wmax, w); wmin = fminf(wmin, w);
        }
        AMX[i * 64 + b] = wmax / sum;
        AMN[i * 64 + b] = wmin / sum;
    } else if (tid >= 64 && tid < 112) {
        int j = tid - 64;
        float m = -3.4e38f;
        for (int i = 0; i < 48; i++) m = fmaxf(m, sc[i][j]);
        float sum = 0.0f, sm = 0.0f;
        for (int i = 0; i < 48; i++) {
            float e = expf(sc[i][j] - m) * x1m[i * 64 + b];
            sum += e; sm += e * x1m[i * 64 + b];
        }
        SS[j * 64 + b] = sm / sum;
    }
}

// ---------------- 8 small fp32 GEMMs: CO[s][64][300] = V[s] @ WcSlice^T ----------------
__global__ __launch_bounds__(256) void coeff_gemm(const float* __restrict__ V,
                                                  const float* __restrict__ Wc,
                                                  float* __restrict__ CO) {
    __shared__ float As[16][64];
    __shared__ float Ws[16][64];
    int s = blockIdx.y;
    const int offs[8] = {0, 600, 600, 1200, 1200, 0, 600, 1200};
    int koff = offs[s];
    const float* A = V + (size_t)s * 38400;
    float* C = CO + (size_t)s * 19200;
    int n0 = blockIdx.x * 64;
    int tid = threadIdx.x;
    int lrow = tid >> 2;
    int lk4 = (tid & 3) << 2;
    int tm = (tid & 15) << 2;
    int tn = (tid >> 4) << 2;
    int nW = n0 + lrow;
    float acc[4][4] = {};
    for (int k0 = 0; k0 < 600; k0 += 16) {
        __syncthreads();
#pragma unroll
        for (int q = 0; q < 4; q++) {
            int k = k0 + lk4 + q;
            As[lk4 + q][lrow] = (k < 600) ? A[lrow * 600 + k] : 0.0f;
            Ws[lk4 + q][lrow] = (k < 600 && nW < 300) ? Wc[(size_t)nW * 1800 + koff + k] : 0.0f;
        }
        __syncthreads();
#pragma unroll
        for (int kk = 0; kk < 16; kk++) {
            float a0 = As[kk][tm], a1 = As[kk][tm + 1], a2 = As[kk][tm + 2], a3 = As[kk][tm + 3];
            float w0 = Ws[kk][tn], w1 = Ws[kk][tn + 1], w2 = Ws[kk][tn + 2], w3 = Ws[kk][tn + 3];
            acc[0][0] += a0 * w0; acc[0][1] += a0 * w1; acc[0][2] += a0 * w2; acc[0][3] += a0 * w3;
            acc[1][0] += a1 * w0; acc[1][1] += a1 * w1; acc[1][2] += a1 * w2; acc[1][3] += a1 * w3;
            acc[2][0] += a2 * w0; acc[2][1] += a2 * w1; acc[2][2] += a2 * w2; acc[2][3] += a2 * w3;
            acc[3][0] += a3 * w0; acc[3][1] += a3 * w1; acc[3][2] += a3 * w2; acc[3][3] += a3 * w3;
        }
    }
#pragma unroll
    for (int ii = 0; ii < 4; ii++) {
        int m = tm + ii;
#pragma unroll
        for (int jn = 0; jn < 4; jn++) {
            int n = n0 + tn + jn;
            if (n < 300) C[m * 300 + n] = acc[ii][jn];
        }
    }
}

// ---------------- rank-combine + relu -> bf16 h1 (t-major [6144][320]) ----------------
__global__ __launch_bounds__(320) void combine_k(const float* __restrict__ CO,
                                                 const float* __restrict__ f1b,
                                                 const float* __restrict__ x1m,
                                                 const float* __restrict__ x2m,
                                                 const float* __restrict__ AMX,
                                                 const float* __restrict__ AMN,
                                                 const float* __restrict__ SS,
                                                 u16* __restrict__ OUT) {
    int r = blockIdx.x;
    int t = r >> 7, bc = r & 127;
    int seq = bc >> 6, b = bc & 63;
    int n = threadIdx.x;
    if (n >= 300) return;
    int bn = b * 300 + n;
    float pre;
    if (seq == 0) {
        float m1 = x1m[t * 64 + b], am = AMX[t * 64 + b], an = AMN[t * 64 + b];
        pre = m1 * CO[bn] + am * CO[19200 + bn] + an * CO[2 * 19200 + bn]
            + m1 * am * CO[3 * 19200 + bn] + m1 * an * CO[4 * 19200 + bn] + f1b[n];
    } else {
        float m2 = x2m[t * 64 + b], sv = SS[t * 64 + b];
        pre = m2 * CO[5 * 19200 + bn] + sv * CO[6 * 19200 + bn]
            + m2 * sv * CO[7 * 19200 + bn] + f1b[n];
    }
    OUT[(size_t)r * KP1 + n] = f2bf(fmaxf(pre, 0.0f));
}

// ---------------- masked mean/max pooling -> pooled^T [2400][64] ----------------
__global__ __launch_bounds__(256) void pool_k(const float* __restrict__ dctx,
                                              const float* __restrict__ x1m,
                                              const float* __restrict__ x2m,
                                              float* __restrict__ pooledT) {
    int idx = blockIdx.x * 256 + threadIdx.x;
    if (idx >= 64 * 2400) return;
    int b = idx / 2400, col = idx % 2400;
    int sec = col / 600, d = col % 600;
    const float* msk = (sec < 2) ? x1m : x2m;
    float v = dctx[((sec < 2 ? 0 : 64) + b) * 600 + d];
    float out;
    if ((sec & 1) == 0) {
        float s = 0, sm = 0;
        for (int t = 0; t < 48; t++) { float mv = msk[t * 64 + b]; s += v * mv; sm += mv; }
        out = s / sm;
    } else {
        float m = -3.4e38f;
        for (int t = 0; t < 48; t++) m = fmaxf(m, v * msk[t * 64 + b]);
        out = m;
    }
    pooledT[col * 64 + b] = out;
}

// ---------------- fc2 + tanh ----------------
__global__ __launch_bounds__(256) void fc2_k2(const float* __restrict__ pooledT,
                                              const float* __restrict__ f2w,
                                              const float* __restrict__ f2b,
                                              float* __restrict__ logit) {
    __shared__ float wl[2400];
    __shared__ float red[256];
    int n = blockIdx.x;
    for (int i = threadIdx.x; i < 2400; i += 256) wl[i] = f2w[n * 2400 + i];
    __syncthreads();
    int b = threadIdx.x & 63, kc = threadIdx.x >> 6;
    float acc = 0.0f;
    int k0 = kc * 600;
    for (int kk = 0; kk < 600; kk++) acc += pooledT[(k0 + kk) * 64 + b] * wl[k0 + kk];
    red[threadIdx.x] = acc;
    __syncthreads();
    if (threadIdx.x < 64) {
        float s = red[b] + red[64 + b] + red[128 + b] + red[192 + b];
        logit[b * 300 + n] = tanhf(s + f2b[n]);
    }
}

// ---------------- output layer ----------------
__global__ __launch_bounds__(64) void out_k2(const float* __restrict__ logit,
                                             const float* __restrict__ fow,
                                             const float* __restrict__ fob,
                                             float* __restrict__ out) {
    int b = blockIdx.x, tid = threadIdx.x;
    float p0 = 0, p1 = 0, p2 = 0;
    for (int k = tid; k < 300; k += 64) {
        float l = logit[b * 300 + k];
        p0 += l * fow[k]; p1 += l * fow[300 + k]; p2 += l * fow[600 + k];
    }
    for (int off = 32; off; off >>= 1) {
        p0 += __shfl_down(p0, off);
        p1 += __shfl_down(p1, off);
        p2 += __shfl_down(p2, off);
    }
    if (tid == 0) {
        out[b * 3 + 0] = p0 + fob[0];
        out[b * 3 + 1] = p1 + fob[1];
        out[b * 3 + 2] = p2 + fob[2];
    }
}

extern "C" void kernel_launch(void* const* d_in, const int* in_sizes, int n_in,
                              void* d_out, int out_size, void* d_ws, size_t ws_size,
                              hipStream_t stream) {
    (void)in_sizes; (void)n_in; (void)out_size; (void)ws_size;
    const int*   x1  = (const int*)d_in[0];
    const float* x1m = (const float*)d_in[1];
    const int*   x2  = (const int*)d_in[2];
    const float* x2m = (const float*)d_in[3];
    const float* emb = (const float*)d_in[5];
    const float* eW  = (const float*)d_in[6];
    const float* eU  = (const float*)d_in[7];
    const float* ebi = (const float*)d_in[8];
    const float* ebh = (const float*)d_in[9];
    const float* rW  = (const float*)d_in[10];
    const float* rU  = (const float*)d_in[11];
    const float* rbi = (const float*)d_in[12];
    const float* rbh = (const float*)d_in[13];
    const float* dW  = (const float*)d_in[14];
    const float* dU  = (const float*)d_in[15];
    const float* dbi = (const float*)d_in[16];
    const float* dbh = (const float*)d_in[17];
    const float* sW  = (const float*)d_in[18];
    const float* sU  = (const float*)d_in[19];
    const float* sbi = (const float*)d_in[20];
    const float* sbh = (const float*)d_in[21];
    const float* f1w = (const float*)d_in[22];
    const float* f1b = (const float*)d_in[23];
    const float* f2w = (const float*)d_in[24];
    const float* f2b = (const float*)d_in[25];
    const float* fow = (const float*)d_in[26];
    const float* fob = (const float*)d_in[27];

    char* wsb = (char*)d_ws;
    u16*       ABF  = (u16*)(wsb + OFF_ABF);
    u16*       WBF  = (u16*)(wsb + OFF_WBF);
    float*     WCF  = (float*)(wsb + OFF_WCF);
    float*     BIAS = (float*)(wsb + OFF_BIAS);
    _Float16*  GFh  = (_Float16*)(wsb + OFF_GF);
    _Float16*  GRh  = (_Float16*)(wsb + OFF_GR);
    u16*       HB   = (u16*)(wsb + OFF_HB);
    float*     ENC  = (float*)(wsb + OFF_ENC);
    float*     VB   = (float*)(wsb + OFF_VB);
    float*     CO   = (float*)(wsb + OFF_CO);
    float*     AMX  = (float*)(wsb + OFF_ATT);
    float*     AMN  = AMX + 3072;
    float*     SS   = AMX + 6144;
    float*     PT   = (float*)(wsb + OFF_PT);
    float*     LG   = (float*)(wsb + OFF_LG);
    u16*       UP   = (u16*)(wsb + OFF_UP);
    u64*       HX64 = (u64*)(wsb + OFF_ABF);   // tagged h-exchange, overlays dead ABF region

    u16* HF0 = HB;
    u16* HR0 = HB + 40960;

    // ---- fused preprocessing (gather + 4xW conv + 4xU perm-direct + bias + fc1 fold) ----
    prep_k<<<dim3(PREP_B4), 256, 0, stream>>>(
        x1, x2, emb, eW, rW, dW, sW, eU, rU, dU, sU,
        ebi, ebh, rbi, rbh, dbi, dbh, sbi, sbh, f1w,
        ABF, WBF, UP, BIAS, WCF);

    // ---- encoder ----
    gemm_bt<<<dim3(48, 10, 2), 256, 0, stream>>>(ABF, WBF, BIAS, GFh, GRh);
    hipMemsetAsync(wsb + OFF_ABF, 0, HX_BYTES, stream);   // after gemms consumed ABF
    lstm_sync<<<dim3(10, 2, 2), 256, 0, stream>>>(GFh, GRh, UP, UP + UPSEG, HX64, HB);

    // ---- attention (rank-1 collapse) + fc1 ----
    enc_k<<<dim3((128 * 600 + 255) / 256), 256, 0, stream>>>(HF0, HR0, ENC);
    vbuf_k<<<dim3((64 * 600 + 255) / 256), 256, 0, stream>>>(ENC, VB);
    attn_lite<<<dim3(64), 256, 0, stream>>>(ENC, x1m, x2m, AMX, AMN, SS);
    coeff_gemm<<<dim3(5, 8), 256, 0, stream>>>(VB, WCF, CO);
    combine_k<<<dim3(6144), 320, 0, stream>>>(CO, f1b, x1m, x2m, AMX, AMN, SS, ABF);

    // ---- decoder ----
    gemm_bt<<<dim3(48, 10, 2), 256, 0, stream>>>(ABF, WBF + 2 * WSEG, BIAS + 2 * NG, GFh, GRh);
    hipMemsetAsync(wsb + OFF_ABF, 0, HX_BYTES, stream);   // after gemms consumed ABF
    lstm_sync<<<dim3(10, 2, 2), 256, 0, stream>>>(GFh, GRh, UP + 2 * UPSEG, UP + 3 * UPSEG, HX64, HB);

    // ---- pooling + classifier ----
    enc_k<<<dim3((128 * 600 + 255) / 256), 256, 0, stream>>>(HF0, HR0, ENC);
    pool_k<<<dim3((64 * 2400 + 255) / 256), 256, 0, stream>>>(ENC, x1m, x2m, PT);
    fc2_k2<<<dim3(300), 256, 0, stream>>>(PT, f2w, f2b, LG);
    out_k2<<<dim3(64), 64, 0, stream>>>(LG, fow, fob, (float*)d_out);
}

// Round 5
// 1040.849 us; speedup vs baseline: 1.2964x; 1.2964x over previous
//
#include <hip/hip_runtime.h>
#include <math.h>

typedef unsigned short u16;
typedef unsigned int u32;
typedef unsigned long long u64;
typedef __attribute__((ext_vector_type(8))) __bf16 bf16x8;
typedef __attribute__((ext_vector_type(4))) float f32x4;
typedef __attribute__((ext_vector_type(4))) _Float16 f16x4;

// ---------------- problem constants ----------------
#define MR   6144      // 48*128 rows (t-major: row = t*128 + bc)
#define KP1  320       // padded K for E=H=300
#define NPG  1280      // padded gate rows (1200 real, interleaved 4j+g)
#define NG   1200
#define WSEG 409600    // u16 elements per weight segment [1280][320]
#define UPSEG 409600   // u16 per U perm segment [80 T][10 kt][64 lane][8]
// G perm (f16 halves): tt*163840 + nt*16384 + half*8192 + wm*4096 + wn*2048 + (i*4+j)*256 + ln*4 + r
#define GT_H 163840

// ---------------- workspace layout (byte offsets, 16B aligned) ----------------
// NOTE: tagged h-exchange buffer HX (655,360 B) lives at OFF_ABF: the ABF region
// is dead during both lstm_sync calls (gemm_bt has fully consumed it), and the
// tag garbage it leaves in ABF's padded k-columns multiplies against zeroed
// B-rows (k>=300) in the next gemm, so it is harmless (and never Inf/NaN).
#define OFF_ABF    0UL           // bf16 [6144][320]            3,932,160
#define OFF_WBF    3932160UL     // bf16 4 x [1280][320]        3,276,800 (W only; U goes straight to UP)
#define OFF_WCF    10485760UL    // f32  [300][1800] folded fc1 2,160,000
#define OFF_BIAS   12645760UL    // f32  4 x 1200 interleaved      19,200
#define OFF_GF     12664960UL    // f16  perm                  15,728,640
#define OFF_GR     28393600UL    // f16  perm                  15,728,640
#define OFF_HB     44122240UL    // bf16 2 dirs x [128][320]      163,840
#define OFF_ENC    44286080UL    // f32  [128][600]               307,200
#define OFF_VB     44593280UL    // f32  8 x [64][600]          1,228,800
#define OFF_CO     45822080UL    // f32  8 x [64][300]            614,400
#define OFF_ATT    46436480UL    // f32  3 x 48*64                 36,864
#define OFF_PT     46473344UL    // f32  [2400][64] pooled^T      614,400
#define OFF_LG     47087744UL    // f32  64*300                    76,800
#define OFF_UP     47164544UL    // bf16 4 x Uperm              3,276,800

#define HX_BYTES   655360UL      // u64 [2 buf][2 dir][128 bcg][160 pair]

__device__ __forceinline__ float fsig(float x) { return 1.0f / (1.0f + __expf(-x)); }
__device__ __forceinline__ float ftanh(float x) { return 1.0f - 2.0f / (__expf(2.0f * x) + 1.0f); }

__device__ __forceinline__ u16 f2bf(float x) {
    union { float f; u32 u; } v; v.f = x;
    u32 r = v.u + 0x7fffu + ((v.u >> 16) & 1u);   // RNE
    return (u16)(r >> 16);
}
__device__ __forceinline__ float bf2f(u16 x) {
    union { u32 u; float f; } v; v.u = ((u32)x) << 16; return v.f;
}

__device__ __forceinline__ void gld_lds16(const u16* g, u16* l) {
    __builtin_amdgcn_global_load_lds(
        (const __attribute__((address_space(1))) unsigned int*)g,
        (__attribute__((address_space(3))) unsigned int*)l, 16, 0, 0);
}

// ---------------- fused preprocessing: gather + wconv(4W) + uperm(4U direct) + bconv + wcat ----
// block-range partition; all five sections are mutually independent (uperm reads fp32 U inputs
// directly instead of the bf16 WBF intermediate, removing the old wconv->uperm dependency).
#define PREP_B0 7680      // gather: MR*KP1/256
#define PREP_B1 14080     // + 4*NPG*KP1/256 = 6400
#define PREP_B2 20480     // + 4*UPSEG/256   = 6400
#define PREP_B3 20499     // + ceil(4*NG/256)= 19
#define PREP_B4 22609     // + ceil(540000/256) = 2110
__global__ __launch_bounds__(256) void prep_k(
    const int* __restrict__ x1, const int* __restrict__ x2, const float* __restrict__ emb,
    const float* __restrict__ w0, const float* __restrict__ w1,
    const float* __restrict__ w2, const float* __restrict__ w3,
    const float* __restrict__ u0, const float* __restrict__ u1,
    const float* __restrict__ u2, const float* __restrict__ u3,
    const float* __restrict__ b0i, const float* __restrict__ b0h,
    const float* __restrict__ b1i, const float* __restrict__ b1h,
    const float* __restrict__ b2i, const float* __restrict__ b2h,
    const float* __restrict__ b3i, const float* __restrict__ b3h,
    const float* __restrict__ f1w,
    u16* __restrict__ abf, u16* __restrict__ wbf, u16* __restrict__ up,
    float* __restrict__ bias, float* __restrict__ wc) {
    int bid = blockIdx.x;
    if (bid < PREP_B0) {
        int idx = bid * 256 + threadIdx.x;          // < MR*KP1 exactly
        int r = idx / KP1, k = idx % KP1;
        float v = 0.0f;
        if (k < 300) {
            int t = r >> 7, bc = r & 127;
            int tok = (bc < 64) ? x1[t * 64 + bc] : x2[t * 64 + bc - 64];
            v = emb[tok * 300 + k];
        }
        abf[idx] = f2bf(v);
    } else if (bid < PREP_B1) {
        int idx = (bid - PREP_B0) * 256 + threadIdx.x;   // < 4*NPG*KP1 exactly
        int s = idx / (NPG * KP1), rem = idx % (NPG * KP1);
        int r = rem / KP1, k = rem % KP1;
        const float* w = (s == 0) ? w0 : (s == 1) ? w1 : (s == 2) ? w2 : w3;
        float v = 0.0f;
        if (r < NG && k < 300) {
            int j = r >> 2, g = r & 3;
            v = w[(g * 300 + j) * 300 + k];
        }
        wbf[idx] = f2bf(v);
    } else if (bid < PREP_B2) {
        int idx = (bid - PREP_B1) * 256 + threadIdx.x;   // < 4*UPSEG exactly
        int seg = idx / UPSEG, pos = idx % UPSEG;
        int T = pos / 5120, kt = (pos / 512) % 10, l = (pos >> 3) & 63, e = pos & 7;
        int n = T * 16 + (l & 15);
        int k = kt * 32 + (l >> 4) * 8 + e;
        const float* us = (seg == 0) ? u0 : (seg == 1) ? u1 : (seg == 2) ? u2 : u3;
        float v = 0.0f;
        if (n < NG && k < 300) {
            int j = n >> 2, g = n & 3;
            v = us[(g * 300 + j) * 300 + k];
        }
        up[idx] = f2bf(v);
    } else if (bid < PREP_B3) {
        int idx = (bid - PREP_B2) * 256 + threadIdx.x;
        if (idx < 4 * NG) {
            int s = idx / NG, n = idx % NG;
            int j = n >> 2, g = n & 3;
            int src = g * 300 + j;
            const float* bi = (s == 0) ? b0i : (s == 1) ? b1i : (s == 2) ? b2i : b3i;
            const float* bh = (s == 0) ? b0h : (s == 1) ? b1h : (s == 2) ? b2h : b3h;
            bias[idx] = bi[src] + bh[src];
        }
    } else {
        int idx = (bid - PREP_B3) * 256 + threadIdx.x;
        if (idx < 300 * 1800) {
            int n = idx / 1800, k = idx % 1800;
            int nk = n * 2400 + k;
            float v;
            if (k < 600)       v = f1w[nk] + f1w[nk + 1800];
            else if (k < 1200) v = f1w[nk] - f1w[nk + 1200];
            else               v = f1w[nk];
            wc[idx] = v;
        }
    }
}

// ---------------- bf16 MFMA GEMM -> G in consumer-fragment-major f16 layout ----------------
// z = weight segment pair member: B = Wb + z*WSEG, bias = biasb + z*NG, out = z ? G1 : G0.
__global__ __launch_bounds__(256) void gemm_bt(const u16* __restrict__ A,
                                               const u16* __restrict__ Wb,
                                               const float* __restrict__ biasb,
                                               _Float16* __restrict__ G0,
                                               _Float16* __restrict__ G1) {
    __shared__ __align__(16) u16 smA[128 * 32];
    __shared__ __align__(16) u16 smB[128 * 32];
    int sidx = blockIdx.z;
    const u16* B = Wb + (size_t)sidx * WSEG;
    const float* bias = biasb + sidx * NG;
    _Float16* Gh = sidx ? G1 : G0;
    int m0 = blockIdx.x * 128, n0 = blockIdx.y * 128;
    int tid = threadIdx.x, ln = tid & 63;
    int wm = (tid >> 6) & 1, wn = tid >> 7;
    int lrow = ln & 15, lq = ln >> 4;
    f32x4 acc[4][4] = {};
    for (int k0 = 0; k0 < KP1; k0 += 32) {
#pragma unroll
        for (int p = 0; p < 2; p++) {
            int e = (p * 256 + tid) * 8;
            int r = e >> 5, kk = e & 31;
            gld_lds16(A + (size_t)(m0 + r) * KP1 + k0 + kk, smA + e);
            gld_lds16(B + (size_t)(n0 + r) * KP1 + k0 + kk, smB + e);
        }
        __syncthreads();
        bf16x8 av[4], bv[4];
#pragma unroll
        for (int i = 0; i < 4; i++) {
            av[i] = *(const bf16x8*)&smA[(wm * 64 + i * 16 + lrow) * 32 + lq * 8];
            bv[i] = *(const bf16x8*)&smB[(wn * 64 + i * 16 + lrow) * 32 + lq * 8];
        }
#pragma unroll
        for (int i = 0; i < 4; i++)
#pragma unroll
            for (int j = 0; j < 4; j++)
                acc[i][j] = __builtin_amdgcn_mfma_f32_16x16x32_bf16(av[i], bv[j], acc[i][j], 0, 0, 0);
        __syncthreads();
    }
    // perm store: half=wm (this wave's 64-row group), consumer wm = i>>1, i' = i&1
    size_t tb = (size_t)blockIdx.x * GT_H + (size_t)blockIdx.y * 16384
              + (size_t)wm * 8192 + (size_t)wn * 2048 + (size_t)ln * 4;
#pragma unroll
    for (int i = 0; i < 4; i++)
#pragma unroll
        for (int j = 0; j < 4; j++) {
            int n = n0 + wn * 64 + j * 16 + lrow;
            f16x4 v;
            if (n < NG) {
                float bb = bias[n];
#pragma unroll
                for (int r = 0; r < 4; r++) v[r] = (_Float16)(acc[i][j][r] + bb);
            } else {
                v = (f16x4)0;
            }
            *(f16x4*)(Gh + tb + (size_t)(i >> 1) * 4096 + (size_t)(((i & 1) * 4 + j)) * 256) = v;
        }
}

// ---------------- LSTM: gate-split, BARRIER-FREE tagged h exchange (R2 structure) ------------
// grid (10 nt, 2 dir, 2 half), block 256 = 4 waves (wm = w&1 batch-quarter, wn = w>>1 gate-half).
// h exchange: u64 {tag=t+1 (hi32), 2xbf16 (lo32)} relaxed agent atomics (8B atomicity => tag-valid
// implies data-valid; no fences/drains/barriers). Poll: full coalesced first pass (40 contiguous
// u64/thread); retries are BATCHED-partial: issue ALL still-missing loads into a register array
// (no intervening uses -> single vmcnt drain, ~1 RTT/pass), then test tags. R4's lesson: testing
// each retry load immediately serializes 40 vmcnt(0) round-trips (518us vs 277us) - never consume
// a poll load before all are issued.
// CRITICAL: h stores are UNCONDITIONAL (incl. padded j>=300 columns, h==0 there): the consumer
// polls all 160 pair-columns, so a guarded store deadlocks the poll (R3 bug).
__global__ __launch_bounds__(256, 1) void lstm_sync(const _Float16* __restrict__ Gf,
                                                    const _Float16* __restrict__ Gr,
                                                    const u16* __restrict__ Upf,
                                                    const u16* __restrict__ Upr,
                                                    u64* __restrict__ hx,
                                                    u16* __restrict__ hb) {
    int nt = blockIdx.x, dir = blockIdx.y, half = blockIdx.z;
    const _Float16* G = dir ? Gr : Gf;
    const u16* Up = dir ? Upr : Upf;

    int tid = threadIdx.x, ln = tid & 63, w = tid >> 6;
    int wm = w & 1, wn = w >> 1;
    int lrow = ln & 15, lq = ln >> 4;

    __shared__ __align__(16) u16 Ulds[80 * 512];    // 8 T x 10 kt x 64 x 8   (80 KB)
    __shared__ __align__(16) u32 Hst[64 * 160];     // tag-stripped h slab     (40 KB)
    __shared__ float P[64][132];                    // gate staging           (33.8 KB)

    // stage this block's U slice (linear copy, fragment-major)
    for (int p = 0; p < 20; p++) {
        int e = (p * 256 + tid) * 8;
        gld_lds16(Up + (size_t)nt * 40960 + e, Ulds + e);
    }
    __syncthreads();

    u32* HOw = (u32*)hb;

    int jp = tid & 15, bg = tid >> 4;
    float c[4][2];
#pragma unroll
    for (int q = 0; q < 4; q++) { c[q][0] = 0.0f; c[q][1] = 0.0f; }

    const _Float16* Gs = G + (size_t)nt * 16384 + (size_t)half * 8192
                       + (size_t)wm * 4096 + (size_t)wn * 2048 + (size_t)ln * 4;
    f16x4 gpre[8];
    {
        int ttg = dir ? 47 : 0;
        const _Float16* Gt = Gs + (size_t)ttg * GT_H;
#pragma unroll
        for (int f = 0; f < 8; f++) gpre[f] = *(const f16x4*)(Gt + (size_t)f * 256);
    }

    for (int t = 0; t < 48; t++) {
        // ---- cooperative tagged poll-load of this half's h slab (64 rows x 160 u64) ----
        {
            const u64* slab = hx + ((size_t)(t & 1) * 2 + dir) * 20480 + (size_t)half * 10240;
            u32 want = (u32)t;
            u32 hv[40];
            u64 miss = 0;
#pragma unroll
            for (int q = 0; q < 40; q++) {
                u64 x = __hip_atomic_load(slab + q * 256 + tid,
                                          __ATOMIC_RELAXED, __HIP_MEMORY_SCOPE_AGENT);
                hv[q] = (u32)x;
                miss |= ((u64)((u32)(x >> 32) != want)) << q;
            }
            while (miss) {
                __builtin_amdgcn_s_sleep(1);
                u64 xs[40];
                // phase 1: issue all missing loads (results NOT consumed here -> pipelined)
#pragma unroll
                for (int q = 0; q < 40; q++)
                    if (miss & (1ull << q))
                        xs[q] = __hip_atomic_load(slab + q * 256 + tid,
                                                  __ATOMIC_RELAXED, __HIP_MEMORY_SCOPE_AGENT);
                // phase 2: single drain, then test tags
#pragma unroll
                for (int q = 0; q < 40; q++)
                    if (miss & (1ull << q)) {
                        if ((u32)(xs[q] >> 32) == want) {
                            hv[q] = (u32)xs[q];
                            miss &= ~(1ull << q);
                        }
                    }
            }
            // strip tags -> XOR-swizzled LDS (write side: consecutive cc per row -> conflict-free)
#pragma unroll
            for (int q = 0; q < 40; q++) {
                int idx = q * 256 + tid;
                int row = idx / 160, cc = idx - row * 160;
                Hst[row * 160 + (cc ^ ((row & 7) << 2))] = hv[q];
            }
        }
        __syncthreads();                             // A: Hst ready, prev-iter frag reads done

        f32x4 acc[2][4];
#pragma unroll
        for (int i = 0; i < 2; i++)
#pragma unroll
            for (int j = 0; j < 4; j++) {
                f32x4 a;
#pragma unroll
                for (int r = 0; r < 4; r++) a[r] = (float)gpre[i * 4 + j][r];
                acc[i][j] = a;
            }

#pragma unroll
        for (int kt = 0; kt < 10; kt++) {
            bf16x8 av[2], bv[4];
#pragma unroll
            for (int i = 0; i < 2; i++) {
                int row = wm * 32 + i * 16 + lrow;
                int cc = (kt * 16 + lq * 4) ^ ((row & 7) << 2);
                av[i] = *(const bf16x8*)&Hst[row * 160 + cc];
            }
#pragma unroll
            for (int j = 0; j < 4; j++)
                bv[j] = *(const bf16x8*)&Ulds[((size_t)(wn * 4 + j) * 10 + kt) * 512 + ln * 8];
#pragma unroll
            for (int i = 0; i < 2; i++)
#pragma unroll
                for (int j = 0; j < 4; j++)
                    acc[i][j] = __builtin_amdgcn_mfma_f32_16x16x32_bf16(av[i], bv[j], acc[i][j], 0, 0, 0);
        }

        // stage gates to LDS
#pragma unroll
        for (int i = 0; i < 2; i++)
#pragma unroll
            for (int j = 0; j < 4; j++) {
                int col = wn * 64 + j * 16 + lrow;
#pragma unroll
                for (int r = 0; r < 4; r++)
                    P[wm * 32 + i * 16 + lq * 4 + r][col] = acc[i][j][r];
            }
        __syncthreads();                             // B: gates staged

        // prefetch next G (coalesced; consumed next iteration)
        if (t < 47) {
            int ttg = dir ? 46 - t : t + 1;
            const _Float16* Gt = Gs + (size_t)ttg * GT_H;
#pragma unroll
            for (int f = 0; f < 8; f++) gpre[f] = *(const f16x4*)(Gt + (size_t)f * 256);
        }

        // nonlinearity: thread owns (bc = bg*4+q, j = nt*32 + 2*jp + {0,1}); c in regs.
        // UNCONDITIONAL store: padded j>=300 have exactly-zero gates -> h == 0 (uniform tags).
        {
            u64* hxo = hx + ((size_t)((t + 1) & 1) * 2 + dir) * 20480;
            u64 tagb = ((u64)(u32)(t + 1)) << 32;
#pragma unroll
            for (int q = 0; q < 4; q++) {
                int bc = bg * 4 + q;
                f32x4 g0 = *(const f32x4*)&P[bc][8 * jp];
                f32x4 g1 = *(const f32x4*)&P[bc][8 * jp + 4];
                float cn0 = fsig(g0[1]) * c[q][0] + fsig(g0[0]) * ftanh(g0[2]);
                float hn0 = fsig(g0[3]) * ftanh(cn0);
                float cn1 = fsig(g1[1]) * c[q][1] + fsig(g1[0]) * ftanh(g1[2]);
                float hn1 = fsig(g1[3]) * ftanh(cn1);
                c[q][0] = cn0; c[q][1] = cn1;
                u32 pk = (u32)f2bf(hn0) | ((u32)f2bf(hn1) << 16);
                int bcg = half * 64 + bc;
                size_t oi = (size_t)bcg * 160 + nt * 16 + jp;
                if (t < 47)
                    __hip_atomic_store(hxo + oi, (u64)pk | tagb,
                                       __ATOMIC_RELAXED, __HIP_MEMORY_SCOPE_AGENT);
                else
                    HOw[(size_t)dir * 20480 + oi] = pk;
            }
        }
        __syncthreads();                             // C: P reads done before next-iter P/Hst writes
    }
}

// ---------------- final-h concat (batch-reversal quirk): [128][600] f32 ----------------
__global__ __launch_bounds__(256) void enc_k(const u16* __restrict__ hF,
                                             const u16* __restrict__ hR,
                                             float* __restrict__ enc) {
    int idx = blockIdx.x * 256 + threadIdx.x;
    if (idx >= 128 * 600) return;
    int bc = idx / 600, d = idx % 600;
    int seq = bc >> 6, b = bc & 63;
    enc[idx] = (d < 300) ? bf2f(hF[bc * KP1 + d])
                         : bf2f(hR[(seq * 64 + 63 - b) * KP1 + d - 300]);
}

// ---------------- build 8 coefficient vectors V[8][64][600] ----------------
__global__ __launch_bounds__(256) void vbuf_k(const float* __restrict__ enc,
                                              float* __restrict__ V) {
    int idx = blockIdx.x * 256 + threadIdx.x;
    if (idx >= 64 * 600) return;
    int b = idx / 600, d = idx % 600;
    float e1 = enc[b * 600 + d], e2 = enc[(64 + b) * 600 + d];
    float p = fmaxf(e2, 0.0f), nn = fminf(e2, 0.0f);
    V[0 * 38400 + idx] = e1;
    V[1 * 38400 + idx] = p;
    V[2 * 38400 + idx] = nn;
    V[3 * 38400 + idx] = e1 * p;
    V[4 * 38400 + idx] = e1 * nn;
    V[5 * 38400 + idx] = e2;
    V[6 * 38400 + idx] = e1;
    V[7 * 38400 + idx] = e1 * e2;
}

// ---------------- attention scalars (rank-1 collapse): AMX/AMN/SS [48][64] ----------------
__global__ __launch_bounds__(256) void attn_lite(const float* __restrict__ enc,
                                                 const float* __restrict__ x1m,
                                                 const float* __restrict__ x2m,
                                                 float* __restrict__ AMX,
                                                 float* __restrict__ AMN,
                                                 float* __restrict__ SS) {
    int b = blockIdx.x, tid = threadIdx.x;
    __shared__ float sc[48][49];
    __shared__ float rmx[4], rmn[4];
    __shared__ float MxMn[2];
    float mx = -3.4e38f, mn = 3.4e38f;
    for (int d = tid; d < 600; d += 256) {
        float p = enc[b * 600 + d] * enc[(64 + b) * 600 + d];
        mx = fmaxf(mx, p); mn = fminf(mn, p);
    }
    for (int off = 32; off; off >>= 1) {
        mx = fmaxf(mx, __shfl_down(mx, off));
        mn = fminf(mn, __shfl_down(mn, off));
    }
    if ((tid & 63) == 0) { rmx[tid >> 6] = mx; rmn[tid >> 6] = mn; }
    __syncthreads();
    if (tid == 0) {
        MxMn[0] = fmaxf(fmaxf(rmx[0], rmx[1]), fmaxf(rmx[2], rmx[3]));
        MxMn[1] = fminf(fminf(rmn[0], rmn[1]), fminf(rmn[2], rmn[3]));
    }
    __syncthreads();
    float Mx = MxMn[0], Mn = MxMn[1];
    for (int idx = tid; idx < 2304; idx += 256) {
        int i = idx / 48, j = idx % 48;
        float q = x1m[i * 64 + b] * x2m[j * 64 + b];
        sc[i][j] = (q > 0.0f) ? q * Mx : ((q < 0.0f) ? q * Mn : 0.0f);
    }
    __syncthreads();
    if (tid < 48) {
        int i = tid;
        float m = -3.4e38f;
        for (int j = 0; j < 48; j++) m = fmaxf(m, sc[i][j]);
        float sum = 0.0f;
        for (int j = 0; j < 48; j++) sum += expf(sc[i][j] - m) * x2m[j * 64 + b];
        float wmax = -3.4e38f, wmin = 3.4e38f;
        for (int j = 0; j < 48; j++) {
            float w = expf(sc[i][j] - m) * x2m[j * 64 + b] * x2m[j * 64 + b];
            wmax = fmaxf(wmax, w); wmin = fminf(wmin, w);
        }
        AMX[i * 64 + b] = wmax / sum;
        AMN[i * 64 + b] = wmin / sum;
    } else if (tid >= 64 && tid < 112) {
        int j = tid - 64;
        float m = -3.4e38f;
        for (int i = 0; i < 48; i++) m = fmaxf(m, sc[i][j]);
        float sum = 0.0f, sm = 0.0f;
        for (int i = 0; i < 48; i++) {
            float e = expf(sc[i][j] - m) * x1m[i * 64 + b];
            sum += e; sm += e * x1m[i * 64 + b];
        }
        SS[j * 64 + b] = sm / sum;
    }
}

// ---------------- 8 small fp32 GEMMs: CO[s][64][300] = V[s] @ WcSlice^T ----------------
__global__ __launch_bounds__(256) void coeff_gemm(const float* __restrict__ V,
                                                  const float* __restrict__ Wc,
                                                  float* __restrict__ CO) {
    __shared__ float As[16][64];
    __shared__ float Ws[16][64];
    int s = blockIdx.y;
    const int offs[8] = {0, 600, 600, 1200, 1200, 0, 600, 1200};
    int koff = offs[s];
    const float* A = V + (size_t)s * 38400;
    float* C = CO + (size_t)s * 19200;
    int n0 = blockIdx.x * 64;
    int tid = threadIdx.x;
    int lrow = tid >> 2;
    int lk4 = (tid & 3) << 2;
    int tm = (tid & 15) << 2;
    int tn = (tid >> 4) << 2;
    int nW = n0 + lrow;
    float acc[4][4] = {};
    for (int k0 = 0; k0 < 600; k0 += 16) {
        __syncthreads();
#pragma unroll
        for (int q = 0; q < 4; q++) {
            int k = k0 + lk4 + q;
            As[lk4 + q][lrow] = (k < 600) ? A[lrow * 600 + k] : 0.0f;
            Ws[lk4 + q][lrow] = (k < 600 && nW < 300) ? Wc[(size_t)nW * 1800 + koff + k] : 0.0f;
        }
        __syncthreads();
#pragma unroll
        for (int kk = 0; kk < 16; kk++) {
            float a0 = As[kk][tm], a1 = As[kk][tm + 1], a2 = As[kk][tm + 2], a3 = As[kk][tm + 3];
            float w0 = Ws[kk][tn], w1 = Ws[kk][tn + 1], w2 = Ws[kk][tn + 2], w3 = Ws[kk][tn + 3];
            acc[0][0] += a0 * w0; acc[0][1] += a0 * w1; acc[0][2] += a0 * w2; acc[0][3] += a0 * w3;
            acc[1][0] += a1 * w0; acc[1][1] += a1 * w1; acc[1][2] += a1 * w2; acc[1][3] += a1 * w3;
            acc[2][0] += a2 * w0; acc[2][1] += a2 * w1; acc[2][2] += a2 * w2; acc[2][3] += a2 * w3;
            acc[3][0] += a3 * w0; acc[3][1] += a3 * w1; acc[3][2] += a3 * w2; acc[3][3] += a3 * w3;
        }
    }
#pragma unroll
    for (int ii = 0; ii < 4; ii++) {
        int m = tm + ii;
#pragma unroll
        for (int jn = 0; jn < 4; jn++) {
            int n = n0 + tn + jn;
            if (n < 300) C[m * 300 + n] = acc[ii][jn];
        }
    }
}

// ---------------- rank-combine + relu -> bf16 h1 (t-major [6144][320]) ----------------
__global__ __launch_bounds__(320) void combine_k(const float* __restrict__ CO,
                                                 const float* __restrict__ f1b,
                                                 const float* __restrict__ x1m,
                                                 const float* __restrict__ x2m,
                                                 const float* __restrict__ AMX,
                                                 const float* __restrict__ AMN,
                                                 const float* __restrict__ SS,
                                                 u16* __restrict__ OUT) {
    int r = blockIdx.x;
    int t = r >> 7, bc = r & 127;
    int seq = bc >> 6, b = bc & 63;
    int n = threadIdx.x;
    if (n >= 300) return;
    int bn = b * 300 + n;
    float pre;
    if (seq == 0) {
        float m1 = x1m[t * 64 + b], am = AMX[t * 64 + b], an = AMN[t * 64 + b];
        pre = m1 * CO[bn] + am * CO[19200 + bn] + an * CO[2 * 19200 + bn]
            + m1 * am * CO[3 * 19200 + bn] + m1 * an * CO[4 * 19200 + bn] + f1b[n];
    } else {
        float m2 = x2m[t * 64 + b], sv = SS[t * 64 + b];
        pre = m2 * CO[5 * 19200 + bn] + sv * CO[6 * 19200 + bn]
            + m2 * sv * CO[7 * 19200 + bn] + f1b[n];
    }
    OUT[(size_t)r * KP1 + n] = f2bf(fmaxf(pre, 0.0f));
}

// ---------------- masked mean/max pooling -> pooled^T [2400][64] ----------------
__global__ __launch_bounds__(256) void pool_k(const float* __restrict__ dctx,
                                              const float* __restrict__ x1m,
                                              const float* __restrict__ x2m,
                                              float* __restrict__ pooledT) {
    int idx = blockIdx.x * 256 + threadIdx.x;
    if (idx >= 64 * 2400) return;
    int b = idx / 2400, col = idx % 2400;
    int sec = col / 600, d = col % 600;
    const float* msk = (sec < 2) ? x1m : x2m;
    float v = dctx[((sec < 2 ? 0 : 64) + b) * 600 + d];
    float out;
    if ((sec & 1) == 0) {
        float s = 0, sm = 0;
        for (int t = 0; t < 48; t++) { float mv = msk[t * 64 + b]; s += v * mv; sm += mv; }
        out = s / sm;
    } else {
        float m = -3.4e38f;
        for (int t = 0; t < 48; t++) m = fmaxf(m, v * msk[t * 64 + b]);
        out = m;
    }
    pooledT[col * 64 + b] = out;
}

// ---------------- fc2 + tanh ----------------
__global__ __launch_bounds__(256) void fc2_k2(const float* __restrict__ pooledT,
                                              const float* __restrict__ f2w,
                                              const float* __restrict__ f2b,
                                              float* __restrict__ logit) {
    __shared__ float wl[2400];
    __shared__ float red[256];
    int n = blockIdx.x;
    for (int i = threadIdx.x; i < 2400; i += 256) wl[i] = f2w[n * 2400 + i];
    __syncthreads();
    int b = threadIdx.x & 63, kc = threadIdx.x >> 6;
    float acc = 0.0f;
    int k0 = kc * 600;
    for (int kk = 0; kk < 600; kk++) acc += pooledT[(k0 + kk) * 64 + b] * wl[k0 + kk];
    red[threadIdx.x] = acc;
    __syncthreads();
    if (threadIdx.x < 64) {
        float s = red[b] + red[64 + b] + red[128 + b] + red[192 + b];
        logit[b * 300 + n] = tanhf(s + f2b[n]);
    }
}

// ---------------- output layer ----------------
__global__ __launch_bounds__(64) void out_k2(const float* __restrict__ logit,
                                             const float* __restrict__ fow,
                                             const float* __restrict__ fob,
                                             float* __restrict__ out) {
    int b = blockIdx.x, tid = threadIdx.x;
    float p0 = 0, p1 = 0, p2 = 0;
    for (int k = tid; k < 300; k += 64) {
        float l = logit[b * 300 + k];
        p0 += l * fow[k]; p1 += l * fow[300 + k]; p2 += l * fow[600 + k];
    }
    for (int off = 32; off; off >>= 1) {
        p0 += __shfl_down(p0, off);
        p1 += __shfl_down(p1, off);
        p2 += __shfl_down(p2, off);
    }
    if (tid == 0) {
        out[b * 3 + 0] = p0 + fob[0];
        out[b * 3 + 1] = p1 + fob[1];
        out[b * 3 + 2] = p2 + fob[2];
    }
}

extern "C" void kernel_launch(void* const* d_in, const int* in_sizes, int n_in,
                              void* d_out, int out_size, void* d_ws, size_t ws_size,
                              hipStream_t stream) {
    (void)in_sizes; (void)n_in; (void)out_size; (void)ws_size;
    const int*   x1  = (const int*)d_in[0];
    const float* x1m = (const float*)d_in[1];
    const int*   x2  = (const int*)d_in[2];
    const float* x2m = (const float*)d_in[3];
    const float* emb = (const float*)d_in[5];
    const float* eW  = (const float*)d_in[6];
    const float* eU  = (const float*)d_in[7];
    const float* ebi = (const float*)d_in[8];
    const float* ebh = (const float*)d_in[9];
    const float* rW  = (const float*)d_in[10];
    const float* rU  = (const float*)d_in[11];
    const float* rbi = (const float*)d_in[12];
    const float* rbh = (const float*)d_in[13];
    const float* dW  = (const float*)d_in[14];
    const float* dU  = (const float*)d_in[15];
    const float* dbi = (const float*)d_in[16];
    const float* dbh = (const float*)d_in[17];
    const float* sW  = (const float*)d_in[18];
    const float* sU  = (const float*)d_in[19];
    const float* sbi = (const float*)d_in[20];
    const float* sbh = (const float*)d_in[21];
    const float* f1w = (const float*)d_in[22];
    const float* f1b = (const float*)d_in[23];
    const float* f2w = (const float*)d_in[24];
    const float* f2b = (const float*)d_in[25];
    const float* fow = (const float*)d_in[26];
    const float* fob = (const float*)d_in[27];

    char* wsb = (char*)d_ws;
    u16*       ABF  = (u16*)(wsb + OFF_ABF);
    u16*       WBF  = (u16*)(wsb + OFF_WBF);
    float*     WCF  = (float*)(wsb + OFF_WCF);
    float*     BIAS = (float*)(wsb + OFF_BIAS);
    _Float16*  GFh  = (_Float16*)(wsb + OFF_GF);
    _Float16*  GRh  = (_Float16*)(wsb + OFF_GR);
    u16*       HB   = (u16*)(wsb + OFF_HB);
    float*     ENC  = (float*)(wsb + OFF_ENC);
    float*     VB   = (float*)(wsb + OFF_VB);
    float*     CO   = (float*)(wsb + OFF_CO);
    float*     AMX  = (float*)(wsb + OFF_ATT);
    float*     AMN  = AMX + 3072;
    float*     SS   = AMX + 6144;
    float*     PT   = (float*)(wsb + OFF_PT);
    float*     LG   = (float*)(wsb + OFF_LG);
    u16*       UP   = (u16*)(wsb + OFF_UP);
    u64*       HX64 = (u64*)(wsb + OFF_ABF);   // tagged h-exchange, overlays dead ABF region

    u16* HF0 = HB;
    u16* HR0 = HB + 40960;

    // ---- fused preprocessing (gather + 4xW conv + 4xU perm-direct + bias + fc1 fold) ----
    prep_k<<<dim3(PREP_B4), 256, 0, stream>>>(
        x1, x2, emb, eW, rW, dW, sW, eU, rU, dU, sU,
        ebi, ebh, rbi, rbh, dbi, dbh, sbi, sbh, f1w,
        ABF, WBF, UP, BIAS, WCF);

    // ---- encoder ----
    gemm_bt<<<dim3(48, 10, 2), 256, 0, stream>>>(ABF, WBF, BIAS, GFh, GRh);
    hipMemsetAsync(wsb + OFF_ABF, 0, HX_BYTES, stream);   // after gemms consumed ABF
    lstm_sync<<<dim3(10, 2, 2), 256, 0, stream>>>(GFh, GRh, UP, UP + UPSEG, HX64, HB);

    // ---- attention (rank-1 collapse) + fc1 ----
    enc_k<<<dim3((128 * 600 + 255) / 256), 256, 0, stream>>>(HF0, HR0, ENC);
    vbuf_k<<<dim3((64 * 600 + 255) / 256), 256, 0, stream>>>(ENC, VB);
    attn_lite<<<dim3(64), 256, 0, stream>>>(ENC, x1m, x2m, AMX, AMN, SS);
    coeff_gemm<<<dim3(5, 8), 256, 0, stream>>>(VB, WCF, CO);
    combine_k<<<dim3(6144), 320, 0, stream>>>(CO, f1b, x1m, x2m, AMX, AMN, SS, ABF);

    // ---- decoder ----
    gemm_bt<<<dim3(48, 10, 2), 256, 0, stream>>>(ABF, WBF + 2 * WSEG, BIAS + 2 * NG, GFh, GRh);
    hipMemsetAsync(wsb + OFF_ABF, 0, HX_BYTES, stream);   // after gemms consumed ABF
    lstm_sync<<<dim3(10, 2, 2), 256, 0, stream>>>(GFh, GRh, UP + 2 * UPSEG, UP + 3 * UPSEG, HX64, HB);

    // ---- pooling + classifier ----
    enc_k<<<dim3((128 * 600 + 255) / 256), 256, 0, stream>>>(HF0, HR0, ENC);
    pool_k<<<dim3((64 * 2400 + 255) / 256), 256, 0, stream>>>(ENC, x1m, x2m, PT);
    fc2_k2<<<dim3(300), 256, 0, stream>>>(PT, f2w, f2b, LG);
    out_k2<<<dim3(64), 64, 0, stream>>>(LG, fow, fob, (float*)d_out);
}

// Round 6
// 856.650 us; speedup vs baseline: 1.5752x; 1.2150x over previous
//
#include <hip/hip_runtime.h>
#include <math.h>

typedef unsigned short u16;
typedef unsigned int u32;
typedef unsigned long long u64;
typedef __attribute__((ext_vector_type(8))) __bf16 bf16x8;
typedef __attribute__((ext_vector_type(4))) float f32x4;
typedef __attribute__((ext_vector_type(4))) _Float16 f16x4;

// ---------------- problem constants ----------------
#define MR   6144      // 48*128 rows (t-major: row = t*128 + bc)
#define KP1  320       // padded K for E=H=300
#define NPG  1280      // padded gate rows (1200 real, interleaved 4j+g)
#define NG   1200
#define WSEG 409600    // u16 elements per weight segment [1280][320]
#define UPSEG 409600   // u16 per U perm segment [80 T][10 kt][64 lane][8]
// G perm (f16 halves): tt*163840 + nt*16384 + half*8192 + wm*4096 + wn*2048 + (i*4+j)*256 + ln*4 + r
#define GT_H 163840

// ---------------- workspace layout (byte offsets, 16B aligned) ----------------
// NOTE: tagged h-exchange buffer HX (655,360 B) lives at OFF_ABF: the ABF region
// is dead during both lstm_sync calls (gemm_bt has fully consumed it), and the
// tag garbage it leaves in ABF's padded k-columns multiplies against zeroed
// B-rows (k>=300) in the next gemm, so it is harmless (and never Inf/NaN).
#define OFF_ABF    0UL           // bf16 [6144][320]            3,932,160
#define OFF_WBF    3932160UL     // bf16 4 x [1280][320]        3,276,800 (W only; U goes straight to UP)
#define OFF_WCF    10485760UL    // f32  [300][1800] folded fc1 2,160,000
#define OFF_BIAS   12645760UL    // f32  4 x 1200 interleaved      19,200
#define OFF_GF     12664960UL    // f16  perm                  15,728,640
#define OFF_GR     28393600UL    // f16  perm                  15,728,640
#define OFF_HB     44122240UL    // bf16 2 dirs x [128][320]      163,840
#define OFF_ENC    44286080UL    // f32  [128][600]               307,200
#define OFF_VB     44593280UL    // f32  8 x [64][600]          1,228,800
#define OFF_CO     45822080UL    // f32  8 x [64][300]            614,400
#define OFF_ATT    46436480UL    // f32  3 x 48*64                 36,864
#define OFF_PT     46473344UL    // f32  [2400][64] pooled^T      614,400
#define OFF_LG     47087744UL    // f32  64*300                    76,800
#define OFF_UP     47164544UL    // bf16 4 x Uperm              3,276,800

#define HX_BYTES   655360UL      // u64 [2 buf][2 dir][128 bcg][160 pair]

__device__ __forceinline__ float fsig(float x) { return 1.0f / (1.0f + __expf(-x)); }
__device__ __forceinline__ float ftanh(float x) { return 1.0f - 2.0f / (__expf(2.0f * x) + 1.0f); }

__device__ __forceinline__ u16 f2bf(float x) {
    union { float f; u32 u; } v; v.f = x;
    u32 r = v.u + 0x7fffu + ((v.u >> 16) & 1u);   // RNE
    return (u16)(r >> 16);
}
__device__ __forceinline__ float bf2f(u16 x) {
    union { u32 u; float f; } v; v.u = ((u32)x) << 16; return v.f;
}

__device__ __forceinline__ void gld_lds16(const u16* g, u16* l) {
    __builtin_amdgcn_global_load_lds(
        (const __attribute__((address_space(1))) unsigned int*)g,
        (__attribute__((address_space(3))) unsigned int*)l, 16, 0, 0);
}

// ---------------- fused preprocessing: gather + wconv(4W) + uperm(4U direct) + bconv + wcat ----
// block-range partition; all five sections are mutually independent (uperm reads fp32 U inputs
// directly instead of the bf16 WBF intermediate, removing the old wconv->uperm dependency).
#define PREP_B0 7680      // gather: MR*KP1/256
#define PREP_B1 14080     // + 4*NPG*KP1/256 = 6400
#define PREP_B2 20480     // + 4*UPSEG/256   = 6400
#define PREP_B3 20499     // + ceil(4*NG/256)= 19
#define PREP_B4 22609     // + ceil(540000/256) = 2110
__global__ __launch_bounds__(256) void prep_k(
    const int* __restrict__ x1, const int* __restrict__ x2, const float* __restrict__ emb,
    const float* __restrict__ w0, const float* __restrict__ w1,
    const float* __restrict__ w2, const float* __restrict__ w3,
    const float* __restrict__ u0, const float* __restrict__ u1,
    const float* __restrict__ u2, const float* __restrict__ u3,
    const float* __restrict__ b0i, const float* __restrict__ b0h,
    const float* __restrict__ b1i, const float* __restrict__ b1h,
    const float* __restrict__ b2i, const float* __restrict__ b2h,
    const float* __restrict__ b3i, const float* __restrict__ b3h,
    const float* __restrict__ f1w,
    u16* __restrict__ abf, u16* __restrict__ wbf, u16* __restrict__ up,
    float* __restrict__ bias, float* __restrict__ wc) {
    int bid = blockIdx.x;
    if (bid < PREP_B0) {
        int idx = bid * 256 + threadIdx.x;          // < MR*KP1 exactly
        int r = idx / KP1, k = idx % KP1;
        float v = 0.0f;
        if (k < 300) {
            int t = r >> 7, bc = r & 127;
            int tok = (bc < 64) ? x1[t * 64 + bc] : x2[t * 64 + bc - 64];
            v = emb[tok * 300 + k];
        }
        abf[idx] = f2bf(v);
    } else if (bid < PREP_B1) {
        int idx = (bid - PREP_B0) * 256 + threadIdx.x;   // < 4*NPG*KP1 exactly
        int s = idx / (NPG * KP1), rem = idx % (NPG * KP1);
        int r = rem / KP1, k = rem % KP1;
        const float* w = (s == 0) ? w0 : (s == 1) ? w1 : (s == 2) ? w2 : w3;
        float v = 0.0f;
        if (r < NG && k < 300) {
            int j = r >> 2, g = r & 3;
            v = w[(g * 300 + j) * 300 + k];
        }
        wbf[idx] = f2bf(v);
    } else if (bid < PREP_B2) {
        int idx = (bid - PREP_B1) * 256 + threadIdx.x;   // < 4*UPSEG exactly
        int seg = idx / UPSEG, pos = idx % UPSEG;
        int T = pos / 5120, kt = (pos / 512) % 10, l = (pos >> 3) & 63, e = pos & 7;
        int n = T * 16 + (l & 15);
        int k = kt * 32 + (l >> 4) * 8 + e;
        const float* us = (seg == 0) ? u0 : (seg == 1) ? u1 : (seg == 2) ? u2 : u3;
        float v = 0.0f;
        if (n < NG && k < 300) {
            int j = n >> 2, g = n & 3;
            v = us[(g * 300 + j) * 300 + k];
        }
        up[idx] = f2bf(v);
    } else if (bid < PREP_B3) {
        int idx = (bid - PREP_B2) * 256 + threadIdx.x;
        if (idx < 4 * NG) {
            int s = idx / NG, n = idx % NG;
            int j = n >> 2, g = n & 3;
            int src = g * 300 + j;
            const float* bi = (s == 0) ? b0i : (s == 1) ? b1i : (s == 2) ? b2i : b3i;
            const float* bh = (s == 0) ? b0h : (s == 1) ? b1h : (s == 2) ? b2h : b3h;
            bias[idx] = bi[src] + bh[src];
        }
    } else {
        int idx = (bid - PREP_B3) * 256 + threadIdx.x;
        if (idx < 300 * 1800) {
            int n = idx / 1800, k = idx % 1800;
            int nk = n * 2400 + k;
            float v;
            if (k < 600)       v = f1w[nk] + f1w[nk + 1800];
            else if (k < 1200) v = f1w[nk] - f1w[nk + 1200];
            else               v = f1w[nk];
            wc[idx] = v;
        }
    }
}

// ---------------- bf16 MFMA GEMM -> G in consumer-fragment-major f16 layout ----------------
// z = weight segment pair member: B = Wb + z*WSEG, bias = biasb + z*NG, out = z ? G1 : G0.
__global__ __launch_bounds__(256) void gemm_bt(const u16* __restrict__ A,
                                               const u16* __restrict__ Wb,
                                               const float* __restrict__ biasb,
                                               _Float16* __restrict__ G0,
                                               _Float16* __restrict__ G1) {
    __shared__ __align__(16) u16 smA[128 * 32];
    __shared__ __align__(16) u16 smB[128 * 32];
    int sidx = blockIdx.z;
    const u16* B = Wb + (size_t)sidx * WSEG;
    const float* bias = biasb + sidx * NG;
    _Float16* Gh = sidx ? G1 : G0;
    int m0 = blockIdx.x * 128, n0 = blockIdx.y * 128;
    int tid = threadIdx.x, ln = tid & 63;
    int wm = (tid >> 6) & 1, wn = tid >> 7;
    int lrow = ln & 15, lq = ln >> 4;
    f32x4 acc[4][4] = {};
    for (int k0 = 0; k0 < KP1; k0 += 32) {
#pragma unroll
        for (int p = 0; p < 2; p++) {
            int e = (p * 256 + tid) * 8;
            int r = e >> 5, kk = e & 31;
            gld_lds16(A + (size_t)(m0 + r) * KP1 + k0 + kk, smA + e);
            gld_lds16(B + (size_t)(n0 + r) * KP1 + k0 + kk, smB + e);
        }
        __syncthreads();
        bf16x8 av[4], bv[4];
#pragma unroll
        for (int i = 0; i < 4; i++) {
            av[i] = *(const bf16x8*)&smA[(wm * 64 + i * 16 + lrow) * 32 + lq * 8];
            bv[i] = *(const bf16x8*)&smB[(wn * 64 + i * 16 + lrow) * 32 + lq * 8];
        }
#pragma unroll
        for (int i = 0; i < 4; i++)
#pragma unroll
            for (int j = 0; j < 4; j++)
                acc[i][j] = __builtin_amdgcn_mfma_f32_16x16x32_bf16(av[i], bv[j], acc[i][j], 0, 0, 0);
        __syncthreads();
    }
    // perm store: half=wm (this wave's 64-row group), consumer wm = i>>1, i' = i&1
    size_t tb = (size_t)blockIdx.x * GT_H + (size_t)blockIdx.y * 16384
              + (size_t)wm * 8192 + (size_t)wn * 2048 + (size_t)ln * 4;
#pragma unroll
    for (int i = 0; i < 4; i++)
#pragma unroll
        for (int j = 0; j < 4; j++) {
            int n = n0 + wn * 64 + j * 16 + lrow;
            f16x4 v;
            if (n < NG) {
                float bb = bias[n];
#pragma unroll
                for (int r = 0; r < 4; r++) v[r] = (_Float16)(acc[i][j][r] + bb);
            } else {
                v = (f16x4)0;
            }
            *(f16x4*)(Gh + tb + (size_t)(i >> 1) * 4096 + (size_t)(((i & 1) * 4 + j)) * 256) = v;
        }
}

// ---------------- LSTM: gate-split, BARRIER-FREE tagged h exchange (R2 poll, 2 barriers) ------
// grid (10 nt, 2 dir, 2 half), block 256 = 4 waves (wm = w&1 batch-quarter, wn = w>>1 gate-half).
// h exchange: u64 {tag=t+1 (hi32), 2xbf16 (lo32)} relaxed agent atomics (8B atomicity => tag-valid
// implies data-valid; no fences/drains/barriers).
// Poll: STRAIGHT-LINE full pass (40 contiguous u64/thread), retry = full re-pass. R4/R5 lesson:
// any per-lane predication on the poll loads creates control flow that blocks the compiler from
// hoisting/batching the loads -> serialized vmcnt round-trips (277 -> 518/373 us). Keep the body
// branch-free so all 40 loads pipeline into ~1 RTT per pass.
// Barriers: A (Hst strip done / prev P reads done) and B (gates staged / Hst reads done). The old
// post-store barrier C is redundant: P-writes are post-next-A, Hst strip-writes are post-B.
// CRITICAL: h stores are UNCONDITIONAL (incl. padded j>=300 columns, h==0 there): the consumer
// polls all 160 pair-columns, so a guarded store deadlocks the poll (R3 bug).
__global__ __launch_bounds__(256, 1) void lstm_sync(const _Float16* __restrict__ Gf,
                                                    const _Float16* __restrict__ Gr,
                                                    const u16* __restrict__ Upf,
                                                    const u16* __restrict__ Upr,
                                                    u64* __restrict__ hx,
                                                    u16* __restrict__ hb) {
    int nt = blockIdx.x, dir = blockIdx.y, half = blockIdx.z;
    const _Float16* G = dir ? Gr : Gf;
    const u16* Up = dir ? Upr : Upf;

    int tid = threadIdx.x, ln = tid & 63, w = tid >> 6;
    int wm = w & 1, wn = w >> 1;
    int lrow = ln & 15, lq = ln >> 4;

    __shared__ __align__(16) u16 Ulds[80 * 512];    // 8 T x 10 kt x 64 x 8   (80 KB)
    __shared__ __align__(16) u32 Hst[64 * 160];     // tag-stripped h slab     (40 KB)
    __shared__ float P[64][132];                    // gate staging           (33.8 KB)

    // stage this block's U slice (linear copy, fragment-major)
    for (int p = 0; p < 20; p++) {
        int e = (p * 256 + tid) * 8;
        gld_lds16(Up + (size_t)nt * 40960 + e, Ulds + e);
    }
    __syncthreads();

    u32* HOw = (u32*)hb;

    int jp = tid & 15, bg = tid >> 4;
    float c[4][2];
#pragma unroll
    for (int q = 0; q < 4; q++) { c[q][0] = 0.0f; c[q][1] = 0.0f; }

    const _Float16* Gs = G + (size_t)nt * 16384 + (size_t)half * 8192
                       + (size_t)wm * 4096 + (size_t)wn * 2048 + (size_t)ln * 4;
    f16x4 gpre[8];
    {
        int ttg = dir ? 47 : 0;
        const _Float16* Gt = Gs + (size_t)ttg * GT_H;
#pragma unroll
        for (int f = 0; f < 8; f++) gpre[f] = *(const f16x4*)(Gt + (size_t)f * 256);
    }

    for (int t = 0; t < 48; t++) {
        // ---- cooperative tagged poll-load of this half's h slab (64 rows x 160 u64) ----
        {
            const u64* slab = hx + ((size_t)(t & 1) * 2 + dir) * 20480 + (size_t)half * 10240;
            u32 want = (u32)t;
            u32 hv[40];
            for (;;) {
                bool ok = true;
#pragma unroll
                for (int q = 0; q < 40; q++) {
                    u64 x = __hip_atomic_load(slab + q * 256 + tid,
                                              __ATOMIC_RELAXED, __HIP_MEMORY_SCOPE_AGENT);
                    hv[q] = (u32)x;
                    ok &= ((u32)(x >> 32) == want);
                }
                if (ok) break;
                __builtin_amdgcn_s_sleep(1);         // backoff only after a failed pass
            }
            // strip tags -> XOR-swizzled LDS (write side: consecutive cc per row -> conflict-free)
#pragma unroll
            for (int q = 0; q < 40; q++) {
                int idx = q * 256 + tid;
                int row = idx / 160, cc = idx - row * 160;
                Hst[row * 160 + (cc ^ ((row & 7) << 2))] = hv[q];
            }
        }
        __syncthreads();                             // A: Hst ready, prev-iter P reads done

        f32x4 acc[2][4];
#pragma unroll
        for (int i = 0; i < 2; i++)
#pragma unroll
            for (int j = 0; j < 4; j++) {
                f32x4 a;
#pragma unroll
                for (int r = 0; r < 4; r++) a[r] = (float)gpre[i * 4 + j][r];
                acc[i][j] = a;
            }

#pragma unroll
        for (int kt = 0; kt < 10; kt++) {
            bf16x8 av[2], bv[4];
#pragma unroll
            for (int i = 0; i < 2; i++) {
                int row = wm * 32 + i * 16 + lrow;
                int cc = (kt * 16 + lq * 4) ^ ((row & 7) << 2);
                av[i] = *(const bf16x8*)&Hst[row * 160 + cc];
            }
#pragma unroll
            for (int j = 0; j < 4; j++)
                bv[j] = *(const bf16x8*)&Ulds[((size_t)(wn * 4 + j) * 10 + kt) * 512 + ln * 8];
#pragma unroll
            for (int i = 0; i < 2; i++)
#pragma unroll
                for (int j = 0; j < 4; j++)
                    acc[i][j] = __builtin_amdgcn_mfma_f32_16x16x32_bf16(av[i], bv[j], acc[i][j], 0, 0, 0);
        }

        // stage gates to LDS
#pragma unroll
        for (int i = 0; i < 2; i++)
#pragma unroll
            for (int j = 0; j < 4; j++) {
                int col = wn * 64 + j * 16 + lrow;
#pragma unroll
                for (int r = 0; r < 4; r++)
                    P[wm * 32 + i * 16 + lq * 4 + r][col] = acc[i][j][r];
            }
        __syncthreads();                             // B: gates staged, Hst reads done

        // prefetch next G (coalesced; consumed next iteration after next barrier A)
        if (t < 47) {
            int ttg = dir ? 46 - t : t + 1;
            const _Float16* Gt = Gs + (size_t)ttg * GT_H;
#pragma unroll
            for (int f = 0; f < 8; f++) gpre[f] = *(const f16x4*)(Gt + (size_t)f * 256);
        }

        // nonlinearity: thread owns (bc = bg*4+q, j = nt*32 + 2*jp + {0,1}); c in regs.
        // UNCONDITIONAL store: padded j>=300 have exactly-zero gates -> h == 0 (uniform tags).
        {
            u64* hxo = hx + ((size_t)((t + 1) & 1) * 2 + dir) * 20480;
            u64 tagb = ((u64)(u32)(t + 1)) << 32;
#pragma unroll
            for (int q = 0; q < 4; q++) {
                int bc = bg * 4 + q;
                f32x4 g0 = *(const f32x4*)&P[bc][8 * jp];
                f32x4 g1 = *(const f32x4*)&P[bc][8 * jp + 4];
                float cn0 = fsig(g0[1]) * c[q][0] + fsig(g0[0]) * ftanh(g0[2]);
                float hn0 = fsig(g0[3]) * ftanh(cn0);
                float cn1 = fsig(g1[1]) * c[q][1] + fsig(g1[0]) * ftanh(g1[2]);
                float hn1 = fsig(g1[3]) * ftanh(cn1);
                c[q][0] = cn0; c[q][1] = cn1;
                u32 pk = (u32)f2bf(hn0) | ((u32)f2bf(hn1) << 16);
                int bcg = half * 64 + bc;
                size_t oi = (size_t)bcg * 160 + nt * 16 + jp;
                if (t < 47)
                    __hip_atomic_store(hxo + oi, (u64)pk | tagb,
                                       __ATOMIC_RELAXED, __HIP_MEMORY_SCOPE_AGENT);
                else
                    HOw[(size_t)dir * 20480 + oi] = pk;
            }
        }
        // no barrier C: P reads (above) vs next P writes ordered by next barrier A;
        // Hst strip writes (next iter, pre-A) vs Hst reads (this iter, pre-B) ordered by B.
    }
}

// ---------------- final-h concat (batch-reversal quirk): [128][600] f32 ----------------
__global__ __launch_bounds__(256) void enc_k(const u16* __restrict__ hF,
                                             const u16* __restrict__ hR,
                                             float* __restrict__ enc) {
    int idx = blockIdx.x * 256 + threadIdx.x;
    if (idx >= 128 * 600) return;
    int bc = idx / 600, d = idx % 600;
    int seq = bc >> 6, b = bc & 63;
    enc[idx] = (d < 300) ? bf2f(hF[bc * KP1 + d])
                         : bf2f(hR[(seq * 64 + 63 - b) * KP1 + d - 300]);
}

// ---------------- build 8 coefficient vectors V[8][64][600] ----------------
__global__ __launch_bounds__(256) void vbuf_k(const float* __restrict__ enc,
                                              float* __restrict__ V) {
    int idx = blockIdx.x * 256 + threadIdx.x;
    if (idx >= 64 * 600) return;
    int b = idx / 600, d = idx % 600;
    float e1 = enc[b * 600 + d], e2 = enc[(64 + b) * 600 + d];
    float p = fmaxf(e2, 0.0f), nn = fminf(e2, 0.0f);
    V[0 * 38400 + idx] = e1;
    V[1 * 38400 + idx] = p;
    V[2 * 38400 + idx] = nn;
    V[3 * 38400 + idx] = e1 * p;
    V[4 * 38400 + idx] = e1 * nn;
    V[5 * 38400 + idx] = e2;
    V[6 * 38400 + idx] = e1;
    V[7 * 38400 + idx] = e1 * e2;
}

// ---------------- attention scalars (rank-1 collapse): AMX/AMN/SS [48][64] ----------------
__global__ __launch_bounds__(256) void attn_lite(const float* __restrict__ enc,
                                                 const float* __restrict__ x1m,
                                                 const float* __restrict__ x2m,
                                                 float* __restrict__ AMX,
                                                 float* __restrict__ AMN,
                                                 float* __restrict__ SS) {
    int b = blockIdx.x, tid = threadIdx.x;
    __shared__ float sc[48][49];
    __shared__ float rmx[4], rmn[4];
    __shared__ float MxMn[2];
    float mx = -3.4e38f, mn = 3.4e38f;
    for (int d = tid; d < 600; d += 256) {
        float p = enc[b * 600 + d] * enc[(64 + b) * 600 + d];
        mx = fmaxf(mx, p); mn = fminf(mn, p);
    }
    for (int off = 32; off; off >>= 1) {
        mx = fmaxf(mx, __shfl_down(mx, off));
        mn = fminf(mn, __shfl_down(mn, off));
    }
    if ((tid & 63) == 0) { rmx[tid >> 6] = mx; rmn[tid >> 6] = mn; }
    __syncthreads();
    if (tid == 0) {
        MxMn[0] = fmaxf(fmaxf(rmx[0], rmx[1]), fmaxf(rmx[2], rmx[3]));
        MxMn[1] = fminf(fminf(rmn[0], rmn[1]), fminf(rmn[2], rmn[3]));
    }
    __syncthreads();
    float Mx = MxMn[0], Mn = MxMn[1];
    for (int idx = tid; idx < 2304; idx += 256) {
        int i = idx / 48, j = idx % 48;
        float q = x1m[i * 64 + b] * x2m[j * 64 + b];
        sc[i][j] = (q > 0.0f) ? q * Mx : ((q < 0.0f) ? q * Mn : 0.0f);
    }
    __syncthreads();
    if (tid < 48) {
        int i = tid;
        float m = -3.4e38f;
        for (int j = 0; j < 48; j++) m = fmaxf(m, sc[i][j]);
        float sum = 0.0f;
        for (int j = 0; j < 48; j++) sum += expf(sc[i][j] - m) * x2m[j * 64 + b];
        float wmax = -3.4e38f, wmin = 3.4e38f;
        for (int j = 0; j < 48; j++) {
            float w = expf(sc[i][j] - m) * x2m[j * 64 + b] * x2m[j * 64 + b];
            wmax = fmaxf(wmax, w); wmin = fminf(wmin, w);
        }
        AMX[i * 64 + b] = wmax / sum;
        AMN[i * 64 + b] = wmin / sum;
    } else if (tid >= 64 && tid < 112) {
        int j = tid - 64;
        float m = -3.4e38f;
        for (int i = 0; i < 48; i++) m = fmaxf(m, sc[i][j]);
        float sum = 0.0f, sm = 0.0f;
        for (int i = 0; i < 48; i++) {
            float e = expf(sc[i][j] - m) * x1m[i * 64 + b];
            sum += e; sm += e * x1m[i * 64 + b];
        }
        SS[j * 64 + b] = sm / sum;
    }
}

// ---------------- 8 small fp32 GEMMs: CO[s][64][300] = V[s] @ WcSlice^T ----------------
__global__ __launch_bounds__(256) void coeff_gemm(const float* __restrict__ V,
                                                  const float* __restrict__ Wc,
                                                  float* __restrict__ CO) {
    __shared__ float As[16][64];
    __shared__ float Ws[16][64];
    int s = blockIdx.y;
    const int offs[8] = {0, 600, 600, 1200, 1200, 0, 600, 1200};
    int koff = offs[s];
    const float* A = V + (size_t)s * 38400;
    float* C = CO + (size_t)s * 19200;
    int n0 = blockIdx.x * 64;
    int tid = threadIdx.x;
    int lrow = tid >> 2;
    int lk4 = (tid & 3) << 2;
    int tm = (tid & 15) << 2;
    int tn = (tid >> 4) << 2;
    int nW = n0 + lrow;
    float acc[4][4] = {};
    for (int k0 = 0; k0 < 600; k0 += 16) {
        __syncthreads();
#pragma unroll
        for (int q = 0; q < 4; q++) {
            int k = k0 + lk4 + q;
            As[lk4 + q][lrow] = (k < 600) ? A[lrow * 600 + k] : 0.0f;
            Ws[lk4 + q][lrow] = (k < 600 && nW < 300) ? Wc[(size_t)nW * 1800 + koff + k] : 0.0f;
        }
        __syncthreads();
#pragma unroll
        for (int kk = 0; kk < 16; kk++) {
            float a0 = As[kk][tm], a1 = As[kk][tm + 1], a2 = As[kk][tm + 2], a3 = As[kk][tm + 3];
            float w0 = Ws[kk][tn], w1 = Ws[kk][tn + 1], w2 = Ws[kk][tn + 2], w3 = Ws[kk][tn + 3];
            acc[0][0] += a0 * w0; acc[0][1] += a0 * w1; acc[0][2] += a0 * w2; acc[0][3] += a0 * w3;
            acc[1][0] += a1 * w0; acc[1][1] += a1 * w1; acc[1][2] += a1 * w2; acc[1][3] += a1 * w3;
            acc[2][0] += a2 * w0; acc[2][1] += a2 * w1; acc[2][2] += a2 * w2; acc[2][3] += a2 * w3;
            acc[3][0] += a3 * w0; acc[3][1] += a3 * w1; acc[3][2] += a3 * w2; acc[3][3] += a3 * w3;
        }
    }
#pragma unroll
    for (int ii = 0; ii < 4; ii++) {
        int m = tm + ii;
#pragma unroll
        for (int jn = 0; jn < 4; jn++) {
            int n = n0 + tn + jn;
            if (n < 300) C[m * 300 + n] = acc[ii][jn];
        }
    }
}

// ---------------- rank-combine + relu -> bf16 h1 (t-major [6144][320]) ----------------
__global__ __launch_bounds__(320) void combine_k(const float* __restrict__ CO,
                                                 const float* __restrict__ f1b,
                                                 const float* __restrict__ x1m,
                                                 const float* __restrict__ x2m,
                                                 const float* __restrict__ AMX,
                                                 const float* __restrict__ AMN,
                                                 const float* __restrict__ SS,
                                                 u16* __restrict__ OUT) {
    int r = blockIdx.x;
    int t = r >> 7, bc = r & 127;
    int seq = bc >> 6, b = bc & 63;
    int n = threadIdx.x;
    if (n >= 300) return;
    int bn = b * 300 + n;
    float pre;
    if (seq == 0) {
        float m1 = x1m[t * 64 + b], am = AMX[t * 64 + b], an = AMN[t * 64 + b];
        pre = m1 * CO[bn] + am * CO[19200 + bn] + an * CO[2 * 19200 + bn]
            + m1 * am * CO[3 * 19200 + bn] + m1 * an * CO[4 * 19200 + bn] + f1b[n];
    } else {
        float m2 = x2m[t * 64 + b], sv = SS[t * 64 + b];
        pre = m2 * CO[5 * 19200 + bn] + sv * CO[6 * 19200 + bn]
            + m2 * sv * CO[7 * 19200 + bn] + f1b[n];
    }
    OUT[(size_t)r * KP1 + n] = f2bf(fmaxf(pre, 0.0f));
}

// ---------------- masked mean/max pooling -> pooled^T [2400][64] ----------------
__global__ __launch_bounds__(256) void pool_k(const float* __restrict__ dctx,
                                              const float* __restrict__ x1m,
                                              const float* __restrict__ x2m,
                                              float* __restrict__ pooledT) {
    int idx = blockIdx.x * 256 + threadIdx.x;
    if (idx >= 64 * 2400) return;
    int b = idx / 2400, col = idx % 2400;
    int sec = col / 600, d = col % 600;
    const float* msk = (sec < 2) ? x1m : x2m;
    float v = dctx[((sec < 2 ? 0 : 64) + b) * 600 + d];
    float out;
    if ((sec & 1) == 0) {
        float s = 0, sm = 0;
        for (int t = 0; t < 48; t++) { float mv = msk[t * 64 + b]; s += v * mv; sm += mv; }
        out = s / sm;
    } else {
        float m = -3.4e38f;
        for (int t = 0; t < 48; t++) m = fmaxf(m, v * msk[t * 64 + b]);
        out = m;
    }
    pooledT[col * 64 + b] = out;
}

// ---------------- fc2 + tanh ----------------
__global__ __launch_bounds__(256) void fc2_k2(const float* __restrict__ pooledT,
                                              const float* __restrict__ f2w,
                                              const float* __restrict__ f2b,
                                              float* __restrict__ logit) {
    __shared__ float wl[2400];
    __shared__ float red[256];
    int n = blockIdx.x;
    for (int i = threadIdx.x; i < 2400; i += 256) wl[i] = f2w[n * 2400 + i];
    __syncthreads();
    int b = threadIdx.x & 63, kc = threadIdx.x >> 6;
    float acc = 0.0f;
    int k0 = kc * 600;
    for (int kk = 0; kk < 600; kk++) acc += pooledT[(k0 + kk) * 64 + b] * wl[k0 + kk];
    red[threadIdx.x] = acc;
    __syncthreads();
    if (threadIdx.x < 64) {
        float s = red[b] + red[64 + b] + red[128 + b] + red[192 + b];
        logit[b * 300 + n] = tanhf(s + f2b[n]);
    }
}

// ---------------- output layer ----------------
__global__ __launch_bounds__(64) void out_k2(const float* __restrict__ logit,
                                             const float* __restrict__ fow,
                                             const float* __restrict__ fob,
                                             float* __restrict__ out) {
    int b = blockIdx.x, tid = threadIdx.x;
    float p0 = 0, p1 = 0, p2 = 0;
    for (int k = tid; k < 300; k += 64) {
        float l = logit[b * 300 + k];
        p0 += l * fow[k]; p1 += l * fow[300 + k]; p2 += l * fow[600 + k];
    }
    for (int off = 32; off; off >>= 1) {
        p0 += __shfl_down(p0, off);
        p1 += __shfl_down(p1, off);
        p2 += __shfl_down(p2, off);
    }
    if (tid == 0) {
        out[b * 3 + 0] = p0 + fob[0];
        out[b * 3 + 1] = p1 + fob[1];
        out[b * 3 + 2] = p2 + fob[2];
    }
}

extern "C" void kernel_launch(void* const* d_in, const int* in_sizes, int n_in,
                              void* d_out, int out_size, void* d_ws, size_t ws_size,
                              hipStream_t stream) {
    (void)in_sizes; (void)n_in; (void)out_size; (void)ws_size;
    const int*   x1  = (const int*)d_in[0];
    const float* x1m = (const float*)d_in[1];
    const int*   x2  = (const int*)d_in[2];
    const float* x2m = (const float*)d_in[3];
    const float* emb = (const float*)d_in[5];
    const float* eW  = (const float*)d_in[6];
    const float* eU  = (const float*)d_in[7];
    const float* ebi = (const float*)d_in[8];
    const float* ebh = (const float*)d_in[9];
    const float* rW  = (const float*)d_in[10];
    const float* rU  = (const float*)d_in[11];
    const float* rbi = (const float*)d_in[12];
    const float* rbh = (const float*)d_in[13];
    const float* dW  = (const float*)d_in[14];
    const float* dU  = (const float*)d_in[15];
    const float* dbi = (const float*)d_in[16];
    const float* dbh = (const float*)d_in[17];
    const float* sW  = (const float*)d_in[18];
    const float* sU  = (const float*)d_in[19];
    const float* sbi = (const float*)d_in[20];
    const float* sbh = (const float*)d_in[21];
    const float* f1w = (const float*)d_in[22];
    const float* f1b = (const float*)d_in[23];
    const float* f2w = (const float*)d_in[24];
    const float* f2b = (const float*)d_in[25];
    const float* fow = (const float*)d_in[26];
    const float* fob = (const float*)d_in[27];

    char* wsb = (char*)d_ws;
    u16*       ABF  = (u16*)(wsb + OFF_ABF);
    u16*       WBF  = (u16*)(wsb + OFF_WBF);
    float*     WCF  = (float*)(wsb + OFF_WCF);
    float*     BIAS = (float*)(wsb + OFF_BIAS);
    _Float16*  GFh  = (_Float16*)(wsb + OFF_GF);
    _Float16*  GRh  = (_Float16*)(wsb + OFF_GR);
    u16*       HB   = (u16*)(wsb + OFF_HB);
    float*     ENC  = (float*)(wsb + OFF_ENC);
    float*     VB   = (float*)(wsb + OFF_VB);
    float*     CO   = (float*)(wsb + OFF_CO);
    float*     AMX  = (float*)(wsb + OFF_ATT);
    float*     AMN  = AMX + 3072;
    float*     SS   = AMX + 6144;
    float*     PT   = (float*)(wsb + OFF_PT);
    float*     LG   = (float*)(wsb + OFF_LG);
    u16*       UP   = (u16*)(wsb + OFF_UP);
    u64*       HX64 = (u64*)(wsb + OFF_ABF);   // tagged h-exchange, overlays dead ABF region

    u16* HF0 = HB;
    u16* HR0 = HB + 40960;

    // ---- fused preprocessing (gather + 4xW conv + 4xU perm-direct + bias + fc1 fold) ----
    prep_k<<<dim3(PREP_B4), 256, 0, stream>>>(
        x1, x2, emb, eW, rW, dW, sW, eU, rU, dU, sU,
        ebi, ebh, rbi, rbh, dbi, dbh, sbi, sbh, f1w,
        ABF, WBF, UP, BIAS, WCF);

    // ---- encoder ----
    gemm_bt<<<dim3(48, 10, 2), 256, 0, stream>>>(ABF, WBF, BIAS, GFh, GRh);
    hipMemsetAsync(wsb + OFF_ABF, 0, HX_BYTES, stream);   // after gemms consumed ABF
    lstm_sync<<<dim3(10, 2, 2), 256, 0, stream>>>(GFh, GRh, UP, UP + UPSEG, HX64, HB);

    // ---- attention (rank-1 collapse) + fc1 ----
    enc_k<<<dim3((128 * 600 + 255) / 256), 256, 0, stream>>>(HF0, HR0, ENC);
    vbuf_k<<<dim3((64 * 600 + 255) / 256), 256, 0, stream>>>(ENC, VB);
    attn_lite<<<dim3(64), 256, 0, stream>>>(ENC, x1m, x2m, AMX, AMN, SS);
    coeff_gemm<<<dim3(5, 8), 256, 0, stream>>>(VB, WCF, CO);
    combine_k<<<dim3(6144), 320, 0, stream>>>(CO, f1b, x1m, x2m, AMX, AMN, SS, ABF);

    // ---- decoder ----
    gemm_bt<<<dim3(48, 10, 2), 256, 0, stream>>>(ABF, WBF + 2 * WSEG, BIAS + 2 * NG, GFh, GRh);
    hipMemsetAsync(wsb + OFF_ABF, 0, HX_BYTES, stream);   // after gemms consumed ABF
    lstm_sync<<<dim3(10, 2, 2), 256, 0, stream>>>(GFh, GRh, UP + 2 * UPSEG, UP + 3 * UPSEG, HX64, HB);

    // ---- pooling + classifier ----
    enc_k<<<dim3((128 * 600 + 255) / 256), 256, 0, stream>>>(HF0, HR0, ENC);
    pool_k<<<dim3((64 * 2400 + 255) / 256), 256, 0, stream>>>(ENC, x1m, x2m, PT);
    fc2_k2<<<dim3(300), 256, 0, stream>>>(PT, f2w, f2b, LG);
    out_k2<<<dim3(64), 64, 0, stream>>>(LG, fow, fob, (float*)d_out);
}